// Round 1
// baseline (917.952 us; speedup 1.0000x reference)
//
#include <hip/hip_runtime.h>
#include <hip/hip_bf16.h>

#define N_NODES 50000
#define E0      800000
#define ET      850000   // E0 + N self-loops? no: E0 + 50000 = 850000
#define IN_F    128
#define HF      256
#define HID     64
#define NEG     0.2f
#define BN_EPSC 1e-5f

__device__ __forceinline__ float lrelu(float x){ return x > 0.f ? x : NEG * x; }

// ---------------- CSR build (dst-sorted edge list, shared by all instances) ----------------
__global__ void k_hist(const int* __restrict__ ei, int* __restrict__ counts){
  int e = blockIdx.x * 256 + threadIdx.x;
  if (e >= ET) return;
  int d = (e < E0) ? ei[E0 + e] : (e - E0);
  atomicAdd(&counts[d], 1);
}

__global__ void k_scan(const int* __restrict__ counts, int* __restrict__ row_ptr,
                       int* __restrict__ cursor){
  __shared__ int psum[256];
  const int CH = 196;                 // 256*196 = 50176 >= 50000
  int t = threadIdx.x;
  int start = t * CH;
  int s = 0;
  for (int j = 0; j < CH; ++j){ int idx = start + j; if (idx < N_NODES) s += counts[idx]; }
  psum[t] = s; __syncthreads();
  if (t == 0){
    int run = 0;
    for (int j = 0; j < 256; ++j){ int v = psum[j]; psum[j] = run; run += v; }
    row_ptr[N_NODES] = run;           // should be ET
  }
  __syncthreads();
  int run = psum[t];
  for (int j = 0; j < CH; ++j){
    int idx = start + j;
    if (idx < N_NODES){ row_ptr[idx] = run; cursor[idx] = run; run += counts[idx]; }
  }
}

__global__ void k_scatter(const int* __restrict__ ei, int* __restrict__ cursor,
                          int* __restrict__ csr_src){
  int e = blockIdx.x * 256 + threadIdx.x;
  if (e >= ET) return;
  int s, d;
  if (e < E0){ s = ei[e]; d = ei[E0 + e]; } else { s = e - E0; d = s; }
  int pos = atomicAdd(&cursor[d], 1);
  csr_src[pos] = s;
}

// ---------------- GEMM1: xw[N,256] = x[N,128] @ W[256,128]^T ----------------
__global__ __launch_bounds__(256) void k_gemm1(const float* __restrict__ A,
                                               const float* __restrict__ B,
                                               float* __restrict__ C){
  __shared__ float As[16][68];
  __shared__ float Bs[16][68];
  int m0 = blockIdx.x * 64, n0 = blockIdx.y * 64;
  int tid = threadIdx.x;
  int tx = tid & 15, ty = tid >> 4;
  int lr = tid >> 2, lk = tid & 3;
  float acc[4][4] = {};
  for (int kc = 0; kc < IN_F; kc += 16){
    float4 av = make_float4(0.f,0.f,0.f,0.f);
    if (m0 + lr < N_NODES) av = *(const float4*)&A[(size_t)(m0 + lr) * IN_F + kc + lk*4];
    float4 bv = *(const float4*)&B[(size_t)(n0 + lr) * IN_F + kc + lk*4];
    As[lk*4+0][lr]=av.x; As[lk*4+1][lr]=av.y; As[lk*4+2][lr]=av.z; As[lk*4+3][lr]=av.w;
    Bs[lk*4+0][lr]=bv.x; Bs[lk*4+1][lr]=bv.y; Bs[lk*4+2][lr]=bv.z; Bs[lk*4+3][lr]=bv.w;
    __syncthreads();
    #pragma unroll
    for (int kk = 0; kk < 16; ++kk){
      float a[4], b[4];
      *(float4*)a = *(const float4*)&As[kk][ty*4];
      *(float4*)b = *(const float4*)&Bs[kk][tx*4];
      #pragma unroll
      for (int i = 0; i < 4; ++i)
        #pragma unroll
        for (int j = 0; j < 4; ++j)
          acc[i][j] += a[i] * b[j];
    }
    __syncthreads();
  }
  #pragma unroll
  for (int i = 0; i < 4; ++i){
    int row = m0 + ty*4 + i;
    if (row < N_NODES){
      float4 v = make_float4(acc[i][0], acc[i][1], acc[i][2], acc[i][3]);
      *(float4*)&C[(size_t)row * HF + n0 + tx*4] = v;
    }
  }
}

// ---------------- alpha_src / alpha_dst: [N,4] each ----------------
__global__ __launch_bounds__(256) void k_alpha(const float* __restrict__ xw,
                       const float* __restrict__ asrc, const float* __restrict__ adst,
                       float* __restrict__ as_, float* __restrict__ ad_){
  int node = blockIdx.x * 4 + (threadIdx.x >> 6);
  int lane = threadIdx.x & 63;
  float4 v = *(const float4*)&xw[(size_t)node * HF + lane*4];
  float4 a = *(const float4*)&asrc[lane*4];
  float4 b = *(const float4*)&adst[lane*4];
  float ts = v.x*a.x + v.y*a.y + v.z*a.z + v.w*a.w;
  float td = v.x*b.x + v.y*b.y + v.z*b.z + v.w*b.w;
  for (int m = 1; m < 16; m <<= 1){ ts += __shfl_xor(ts, m, 64); td += __shfl_xor(td, m, 64); }
  if ((lane & 15) == 0){ int h = lane >> 4; as_[node*4 + h] = ts; ad_[node*4 + h] = td; }
}

// ---------------- aggregation: segment softmax + weighted gather, one wave/node ----------------
__global__ __launch_bounds__(256) void k_agg(const float* __restrict__ xw,
                     const float* __restrict__ as_, const float* __restrict__ ad_,
                     const int* __restrict__ row_ptr, const int* __restrict__ csr_src,
                     const float* __restrict__ bias, float* __restrict__ outb){
  int node = blockIdx.x * 4 + (threadIdx.x >> 6);
  int lane = threadIdx.x & 63;
  int row0 = row_ptr[node], row1 = row_ptr[node + 1];
  int deg = row1 - row0;
  float4 ad4 = *(const float4*)&ad_[node*4];
  float m0=-1e30f, m1=-1e30f, m2=-1e30f, m3=-1e30f;
  for (int j = lane; j < deg; j += 64){
    int s = csr_src[row0 + j];
    float4 a4 = *(const float4*)&as_[s*4];
    m0 = fmaxf(m0, lrelu(a4.x + ad4.x));
    m1 = fmaxf(m1, lrelu(a4.y + ad4.y));
    m2 = fmaxf(m2, lrelu(a4.z + ad4.z));
    m3 = fmaxf(m3, lrelu(a4.w + ad4.w));
  }
  for (int m = 1; m < 64; m <<= 1){
    m0 = fmaxf(m0, __shfl_xor(m0, m, 64));
    m1 = fmaxf(m1, __shfl_xor(m1, m, 64));
    m2 = fmaxf(m2, __shfl_xor(m2, m, 64));
    m3 = fmaxf(m3, __shfl_xor(m3, m, 64));
  }
  float s0=0.f, s1=0.f, s2=0.f, s3=0.f;
  for (int j = lane; j < deg; j += 64){
    int s = csr_src[row0 + j];
    float4 a4 = *(const float4*)&as_[s*4];
    s0 += __expf(lrelu(a4.x + ad4.x) - m0);
    s1 += __expf(lrelu(a4.y + ad4.y) - m1);
    s2 += __expf(lrelu(a4.z + ad4.z) - m2);
    s3 += __expf(lrelu(a4.w + ad4.w) - m3);
  }
  for (int m = 1; m < 64; m <<= 1){
    s0 += __shfl_xor(s0, m, 64);
    s1 += __shfl_xor(s1, m, 64);
    s2 += __shfl_xor(s2, m, 64);
    s3 += __shfl_xor(s3, m, 64);
  }
  int h = lane >> 4;
  float mh  = (h==0) ? m0 : (h==1) ? m1 : (h==2) ? m2 : m3;
  float sh  = (h==0) ? s0 : (h==1) ? s1 : (h==2) ? s2 : s3;
  float adh = (h==0) ? ad4.x : (h==1) ? ad4.y : (h==2) ? ad4.z : ad4.w;
  float invh = 1.f / (sh + 1e-16f);
  float accx=0.f, accy=0.f, accz=0.f, accw=0.f;
  for (int jb = 0; jb < deg; jb += 64){
    int sreg = (jb + lane < deg) ? csr_src[row0 + jb + lane] : 0;
    int lim = min(64, deg - jb);
    for (int q = 0; q < lim; ++q){
      int s = __shfl(sreg, q, 64);
      float asv = as_[s*4 + h];
      float w = __expf(lrelu(asv + adh) - mh) * invh;
      float4 v = *(const float4*)&xw[(size_t)s * HF + lane*4];
      accx += w * v.x; accy += w * v.y; accz += w * v.z; accw += w * v.w;
    }
  }
  float4 b4 = *(const float4*)&bias[lane*4];
  float4 o = make_float4(accx + b4.x, accy + b4.y, accz + b4.z, accw + b4.w);
  *(float4*)&outb[(size_t)node * HF + lane*4] = o;
}

// ---------------- GEMM2: allemb[N,64] += BNReLU(outb)[N,256] @ linW[64,256]^T + linb ----------------
__global__ __launch_bounds__(256) void k_gemm2(const float* __restrict__ A,
                     const float* __restrict__ B,
                     const float* __restrict__ mean, const float* __restrict__ var,
                     const float* __restrict__ gamma, const float* __restrict__ beta,
                     const float* __restrict__ linb, float* __restrict__ allemb){
  __shared__ float As[16][68];
  __shared__ float Bs[16][68];
  int m0 = blockIdx.x * 64;
  int tid = threadIdx.x;
  int tx = tid & 15, ty = tid >> 4;
  int lr = tid >> 2, lk = tid & 3;
  float acc[4][4] = {};
  for (int kc = 0; kc < HF; kc += 16){
    int kb = kc + lk*4;
    float4 av = make_float4(0.f,0.f,0.f,0.f);
    if (m0 + lr < N_NODES) av = *(const float4*)&A[(size_t)(m0 + lr) * HF + kb];
    float4 mn = *(const float4*)&mean[kb];
    float4 vr = *(const float4*)&var[kb];
    float4 gm = *(const float4*)&gamma[kb];
    float4 bt = *(const float4*)&beta[kb];
    float4 y;
    y.x = fmaxf(0.f, (av.x - mn.x) * (gm.x * rsqrtf(vr.x + BN_EPSC)) + bt.x);
    y.y = fmaxf(0.f, (av.y - mn.y) * (gm.y * rsqrtf(vr.y + BN_EPSC)) + bt.y);
    y.z = fmaxf(0.f, (av.z - mn.z) * (gm.z * rsqrtf(vr.z + BN_EPSC)) + bt.z);
    y.w = fmaxf(0.f, (av.w - mn.w) * (gm.w * rsqrtf(vr.w + BN_EPSC)) + bt.w);
    float4 bv = *(const float4*)&B[(size_t)lr * HF + kb];   // B is [64][256]
    As[lk*4+0][lr]=y.x; As[lk*4+1][lr]=y.y; As[lk*4+2][lr]=y.z; As[lk*4+3][lr]=y.w;
    Bs[lk*4+0][lr]=bv.x; Bs[lk*4+1][lr]=bv.y; Bs[lk*4+2][lr]=bv.z; Bs[lk*4+3][lr]=bv.w;
    __syncthreads();
    #pragma unroll
    for (int kk = 0; kk < 16; ++kk){
      float a[4], b[4];
      *(float4*)a = *(const float4*)&As[kk][ty*4];
      *(float4*)b = *(const float4*)&Bs[kk][tx*4];
      #pragma unroll
      for (int i = 0; i < 4; ++i)
        #pragma unroll
        for (int j = 0; j < 4; ++j)
          acc[i][j] += a[i] * b[j];
    }
    __syncthreads();
  }
  #pragma unroll
  for (int i = 0; i < 4; ++i){
    int row = m0 + ty*4 + i;
    if (row < N_NODES){
      #pragma unroll
      for (int j = 0; j < 4; ++j){
        int col = tx*4 + j;
        allemb[(size_t)row * HID + col] += acc[i][j] + linb[col];
      }
    }
  }
}

// ---------------- final row L2 normalize ----------------
__global__ __launch_bounds__(256) void k_norm(const float* __restrict__ allemb, float* __restrict__ out){
  int node = blockIdx.x * 4 + (threadIdx.x >> 6);
  int lane = threadIdx.x & 63;
  float v = allemb[(size_t)node * HID + lane];
  float ss = v * v;
  for (int m = 1; m < 64; m <<= 1) ss += __shfl_xor(ss, m, 64);
  out[(size_t)node * HID + lane] = v / sqrtf(ss);
}

extern "C" void kernel_launch(void* const* d_in, const int* in_sizes, int n_in,
                              void* d_out, int out_size, void* d_ws, size_t ws_size,
                              hipStream_t stream){
  const float* sppmi   = (const float*)d_in[0];   // [3][50000][128]
  const float* W       = (const float*)d_in[1];   // [3][256][128]
  const float* att_src = (const float*)d_in[2];   // [3][256]
  const float* att_dst = (const float*)d_in[3];   // [3][256]
  const float* bias    = (const float*)d_in[4];   // [3][256]
  const float* bn_g    = (const float*)d_in[5];
  const float* bn_b    = (const float*)d_in[6];
  const float* bn_m    = (const float*)d_in[7];
  const float* bn_v    = (const float*)d_in[8];
  const float* lin_W   = (const float*)d_in[9];   // [3][64][256]
  const float* lin_b   = (const float*)d_in[10];  // [3][64]
  const int*   ei      = (const int*)d_in[11];    // [2][800000]

  char* ws = (char*)d_ws;
  size_t off = 0;
  auto alloc = [&](size_t bytes)->char*{ char* p = ws + off; off += (bytes + 255) & ~(size_t)255; return p; };
  float* xw     = (float*)alloc((size_t)N_NODES * HF * 4);
  float* outb   = (float*)alloc((size_t)N_NODES * HF * 4);
  float* as_    = (float*)alloc((size_t)N_NODES * 4 * 4);
  float* ad_    = (float*)alloc((size_t)N_NODES * 4 * 4);
  float* allemb = (float*)alloc((size_t)N_NODES * HID * 4);
  int* counts   = (int*)alloc((size_t)N_NODES * 4);
  int* row_ptr  = (int*)alloc((size_t)(N_NODES + 4) * 4);
  int* cursor   = (int*)alloc((size_t)N_NODES * 4);
  int* csr      = (int*)alloc((size_t)ET * 4);

  hipMemsetAsync(counts, 0, (size_t)N_NODES * 4, stream);
  hipMemsetAsync(allemb, 0, (size_t)N_NODES * HID * 4, stream);

  k_hist<<<(ET + 255) / 256, 256, 0, stream>>>(ei, counts);
  k_scan<<<1, 256, 0, stream>>>(counts, row_ptr, cursor);
  k_scatter<<<(ET + 255) / 256, 256, 0, stream>>>(ei, cursor, csr);

  for (int i = 0; i < 3; ++i){
    k_gemm1<<<dim3(782, 4), 256, 0, stream>>>(sppmi + (size_t)i * N_NODES * IN_F,
                                              W + (size_t)i * HF * IN_F, xw);
    k_alpha<<<12500, 256, 0, stream>>>(xw, att_src + i * 256, att_dst + i * 256, as_, ad_);
    k_agg<<<12500, 256, 0, stream>>>(xw, as_, ad_, row_ptr, csr, bias + i * 256, outb);
    k_gemm2<<<782, 256, 0, stream>>>(outb, lin_W + (size_t)i * HID * HF,
                                     bn_m + i * 256, bn_v + i * 256, bn_g + i * 256, bn_b + i * 256,
                                     lin_b + i * 64, allemb);
  }
  k_norm<<<12500, 256, 0, stream>>>(allemb, (float*)d_out);
}

// Round 2
// 794.462 us; speedup vs baseline: 1.1554x; 1.1554x over previous
//
#include <hip/hip_runtime.h>
#include <hip/hip_bf16.h>

#define N_NODES 50000
#define E0      800000
#define ET      850000   // E0 + N_NODES self-loops
#define IN_F    128
#define HF      256
#define HID     64
#define NEG     0.2f
#define BN_EPSC 1e-5f
#define NSCAN_BLK 196    // ceil(50000/256)

__device__ __forceinline__ float lrelu(float x){ return x > 0.f ? x : NEG * x; }

// ---------------- CSR build (dst-sorted edge list, shared by all instances) ----------------
__global__ void k_hist(const int* __restrict__ ei, int* __restrict__ counts){
  int e = blockIdx.x * 256 + threadIdx.x;
  if (e >= ET) return;
  int d = (e < E0) ? ei[E0 + e] : (e - E0);
  atomicAdd(&counts[d], 1);
}

// Parallel scan, stage 1: per-block sums of counts (256 entries per block)
__global__ __launch_bounds__(256) void k_bsum(const int* __restrict__ counts, int* __restrict__ bsums){
  int b = blockIdx.x;
  int t = threadIdx.x;
  int idx = b * 256 + t;
  int v = (idx < N_NODES) ? counts[idx] : 0;
  // wave reduce
  for (int m = 1; m < 64; m <<= 1) v += __shfl_xor(v, m, 64);
  __shared__ int ws[4];
  int lane = t & 63, w = t >> 6;
  if (lane == 0) ws[w] = v;
  __syncthreads();
  if (t == 0) bsums[b] = ws[0] + ws[1] + ws[2] + ws[3];
}

// stage 2: exclusive scan of the 196 block sums (single small block, all parallel)
__global__ __launch_bounds__(256) void k_bscan(const int* __restrict__ bsums, int* __restrict__ bexcl,
                                               int* __restrict__ row_ptr){
  int t = threadIdx.x;
  int v = (t < NSCAN_BLK) ? bsums[t] : 0;
  int lane = t & 63, w = t >> 6;
  // wave inclusive scan
  int incl = v;
  for (int m = 1; m < 64; m <<= 1){
    int n = __shfl_up(incl, m, 64);
    if (lane >= m) incl += n;
  }
  __shared__ int ws[4];
  if (lane == 63) ws[w] = incl;
  __syncthreads();
  if (t == 0){
    int r = 0;
    for (int j = 0; j < 4; ++j){ int x = ws[j]; ws[j] = r; r += x; }
  }
  __syncthreads();
  int excl = incl - v + ws[w];
  if (t < NSCAN_BLK) bexcl[t] = excl;
  if (t == 255) row_ptr[N_NODES] = excl + v;   // total (== ET)
}

// stage 3: per-block exclusive scan + block offset -> row_ptr / cursor
__global__ __launch_bounds__(256) void k_sfinal(const int* __restrict__ counts,
                                                const int* __restrict__ bexcl,
                                                int* __restrict__ row_ptr, int* __restrict__ cursor){
  int b = blockIdx.x;
  int t = threadIdx.x;
  int idx = b * 256 + t;
  int v = (idx < N_NODES) ? counts[idx] : 0;
  int lane = t & 63, w = t >> 6;
  int incl = v;
  for (int m = 1; m < 64; m <<= 1){
    int n = __shfl_up(incl, m, 64);
    if (lane >= m) incl += n;
  }
  __shared__ int ws[4];
  if (lane == 63) ws[w] = incl;
  __syncthreads();
  if (t == 0){
    int r = 0;
    for (int j = 0; j < 4; ++j){ int x = ws[j]; ws[j] = r; r += x; }
  }
  __syncthreads();
  int excl = incl - v + ws[w];
  int pos = bexcl[b] + excl;
  if (idx < N_NODES){ row_ptr[idx] = pos; cursor[idx] = pos; }
}

__global__ void k_scatter(const int* __restrict__ ei, int* __restrict__ cursor,
                          int* __restrict__ csr_src){
  int e = blockIdx.x * 256 + threadIdx.x;
  if (e >= ET) return;
  int s, d;
  if (e < E0){ s = ei[e]; d = ei[E0 + e]; } else { s = e - E0; d = s; }
  int pos = atomicAdd(&cursor[d], 1);
  csr_src[pos] = s;
}

// ---------------- GEMM1: xw[N,256] = x[N,128] @ W[256,128]^T ----------------
__global__ __launch_bounds__(256) void k_gemm1(const float* __restrict__ A,
                                               const float* __restrict__ B,
                                               float* __restrict__ C){
  __shared__ float As[16][68];
  __shared__ float Bs[16][68];
  int m0 = blockIdx.x * 64, n0 = blockIdx.y * 64;
  int tid = threadIdx.x;
  int tx = tid & 15, ty = tid >> 4;
  int lr = tid >> 2, lk = tid & 3;
  float acc[4][4] = {};
  for (int kc = 0; kc < IN_F; kc += 16){
    float4 av = make_float4(0.f,0.f,0.f,0.f);
    if (m0 + lr < N_NODES) av = *(const float4*)&A[(size_t)(m0 + lr) * IN_F + kc + lk*4];
    float4 bv = *(const float4*)&B[(size_t)(n0 + lr) * IN_F + kc + lk*4];
    As[lk*4+0][lr]=av.x; As[lk*4+1][lr]=av.y; As[lk*4+2][lr]=av.z; As[lk*4+3][lr]=av.w;
    Bs[lk*4+0][lr]=bv.x; Bs[lk*4+1][lr]=bv.y; Bs[lk*4+2][lr]=bv.z; Bs[lk*4+3][lr]=bv.w;
    __syncthreads();
    #pragma unroll
    for (int kk = 0; kk < 16; ++kk){
      float a[4], b[4];
      *(float4*)a = *(const float4*)&As[kk][ty*4];
      *(float4*)b = *(const float4*)&Bs[kk][tx*4];
      #pragma unroll
      for (int i = 0; i < 4; ++i)
        #pragma unroll
        for (int j = 0; j < 4; ++j)
          acc[i][j] += a[i] * b[j];
    }
    __syncthreads();
  }
  #pragma unroll
  for (int i = 0; i < 4; ++i){
    int row = m0 + ty*4 + i;
    if (row < N_NODES){
      float4 v = make_float4(acc[i][0], acc[i][1], acc[i][2], acc[i][3]);
      *(float4*)&C[(size_t)row * HF + n0 + tx*4] = v;
    }
  }
}

// ---------------- alpha_src / alpha_dst: [N,4] each ----------------
__global__ __launch_bounds__(256) void k_alpha(const float* __restrict__ xw,
                       const float* __restrict__ asrc, const float* __restrict__ adst,
                       float* __restrict__ as_, float* __restrict__ ad_){
  int node = blockIdx.x * 4 + (threadIdx.x >> 6);
  int lane = threadIdx.x & 63;
  float4 v = *(const float4*)&xw[(size_t)node * HF + lane*4];
  float4 a = *(const float4*)&asrc[lane*4];
  float4 b = *(const float4*)&adst[lane*4];
  float ts = v.x*a.x + v.y*a.y + v.z*a.z + v.w*a.w;
  float td = v.x*b.x + v.y*b.y + v.z*b.z + v.w*b.w;
  for (int m = 1; m < 16; m <<= 1){ ts += __shfl_xor(ts, m, 64); td += __shfl_xor(td, m, 64); }
  if ((lane & 15) == 0){ int h = lane >> 4; as_[node*4 + h] = ts; ad_[node*4 + h] = td; }
}

// ---------------- aggregation: segment softmax + weighted gather, one wave/node ----------------
__global__ __launch_bounds__(256) void k_agg(const float* __restrict__ xw,
                     const float* __restrict__ as_, const float* __restrict__ ad_,
                     const int* __restrict__ row_ptr, const int* __restrict__ csr_src,
                     const float* __restrict__ bias, float* __restrict__ outb){
  int node = blockIdx.x * 4 + (threadIdx.x >> 6);
  int lane = threadIdx.x & 63;
  int row0 = row_ptr[node], row1 = row_ptr[node + 1];
  int deg = row1 - row0;
  float4 ad4 = *(const float4*)&ad_[node*4];
  float m0=-1e30f, m1=-1e30f, m2=-1e30f, m3=-1e30f;
  for (int j = lane; j < deg; j += 64){
    int s = csr_src[row0 + j];
    float4 a4 = *(const float4*)&as_[s*4];
    m0 = fmaxf(m0, lrelu(a4.x + ad4.x));
    m1 = fmaxf(m1, lrelu(a4.y + ad4.y));
    m2 = fmaxf(m2, lrelu(a4.z + ad4.z));
    m3 = fmaxf(m3, lrelu(a4.w + ad4.w));
  }
  for (int m = 1; m < 64; m <<= 1){
    m0 = fmaxf(m0, __shfl_xor(m0, m, 64));
    m1 = fmaxf(m1, __shfl_xor(m1, m, 64));
    m2 = fmaxf(m2, __shfl_xor(m2, m, 64));
    m3 = fmaxf(m3, __shfl_xor(m3, m, 64));
  }
  float s0=0.f, s1=0.f, s2=0.f, s3=0.f;
  for (int j = lane; j < deg; j += 64){
    int s = csr_src[row0 + j];
    float4 a4 = *(const float4*)&as_[s*4];
    s0 += __expf(lrelu(a4.x + ad4.x) - m0);
    s1 += __expf(lrelu(a4.y + ad4.y) - m1);
    s2 += __expf(lrelu(a4.z + ad4.z) - m2);
    s3 += __expf(lrelu(a4.w + ad4.w) - m3);
  }
  for (int m = 1; m < 64; m <<= 1){
    s0 += __shfl_xor(s0, m, 64);
    s1 += __shfl_xor(s1, m, 64);
    s2 += __shfl_xor(s2, m, 64);
    s3 += __shfl_xor(s3, m, 64);
  }
  int h = lane >> 4;
  float mh  = (h==0) ? m0 : (h==1) ? m1 : (h==2) ? m2 : m3;
  float sh  = (h==0) ? s0 : (h==1) ? s1 : (h==2) ? s2 : s3;
  float adh = (h==0) ? ad4.x : (h==1) ? ad4.y : (h==2) ? ad4.z : ad4.w;
  float invh = 1.f / (sh + 1e-16f);
  float accx=0.f, accy=0.f, accz=0.f, accw=0.f;
  for (int jb = 0; jb < deg; jb += 64){
    int sreg = (jb + lane < deg) ? csr_src[row0 + jb + lane] : 0;
    int lim = min(64, deg - jb);
    for (int q = 0; q < lim; ++q){
      int s = __shfl(sreg, q, 64);
      float asv = as_[s*4 + h];
      float w = __expf(lrelu(asv + adh) - mh) * invh;
      float4 v = *(const float4*)&xw[(size_t)s * HF + lane*4];
      accx += w * v.x; accy += w * v.y; accz += w * v.z; accw += w * v.w;
    }
  }
  float4 b4 = *(const float4*)&bias[lane*4];
  float4 o = make_float4(accx + b4.x, accy + b4.y, accz + b4.z, accw + b4.w);
  *(float4*)&outb[(size_t)node * HF + lane*4] = o;
}

// ---------------- GEMM2: allemb[N,64] += BNReLU(outb)[N,256] @ linW[64,256]^T + linb ----------------
__global__ __launch_bounds__(256) void k_gemm2(const float* __restrict__ A,
                     const float* __restrict__ B,
                     const float* __restrict__ mean, const float* __restrict__ var,
                     const float* __restrict__ gamma, const float* __restrict__ beta,
                     const float* __restrict__ linb, float* __restrict__ allemb){
  __shared__ float As[16][68];
  __shared__ float Bs[16][68];
  int m0 = blockIdx.x * 64;
  int tid = threadIdx.x;
  int tx = tid & 15, ty = tid >> 4;
  int lr = tid >> 2, lk = tid & 3;
  float acc[4][4] = {};
  for (int kc = 0; kc < HF; kc += 16){
    int kb = kc + lk*4;
    float4 av = make_float4(0.f,0.f,0.f,0.f);
    if (m0 + lr < N_NODES) av = *(const float4*)&A[(size_t)(m0 + lr) * HF + kb];
    float4 mn = *(const float4*)&mean[kb];
    float4 vr = *(const float4*)&var[kb];
    float4 gm = *(const float4*)&gamma[kb];
    float4 bt = *(const float4*)&beta[kb];
    float4 y;
    y.x = fmaxf(0.f, (av.x - mn.x) * (gm.x * rsqrtf(vr.x + BN_EPSC)) + bt.x);
    y.y = fmaxf(0.f, (av.y - mn.y) * (gm.y * rsqrtf(vr.y + BN_EPSC)) + bt.y);
    y.z = fmaxf(0.f, (av.z - mn.z) * (gm.z * rsqrtf(vr.z + BN_EPSC)) + bt.z);
    y.w = fmaxf(0.f, (av.w - mn.w) * (gm.w * rsqrtf(vr.w + BN_EPSC)) + bt.w);
    float4 bv = *(const float4*)&B[(size_t)lr * HF + kb];   // B is [64][256]
    As[lk*4+0][lr]=y.x; As[lk*4+1][lr]=y.y; As[lk*4+2][lr]=y.z; As[lk*4+3][lr]=y.w;
    Bs[lk*4+0][lr]=bv.x; Bs[lk*4+1][lr]=bv.y; Bs[lk*4+2][lr]=bv.z; Bs[lk*4+3][lr]=bv.w;
    __syncthreads();
    #pragma unroll
    for (int kk = 0; kk < 16; ++kk){
      float a[4], b[4];
      *(float4*)a = *(const float4*)&As[kk][ty*4];
      *(float4*)b = *(const float4*)&Bs[kk][tx*4];
      #pragma unroll
      for (int i = 0; i < 4; ++i)
        #pragma unroll
        for (int j = 0; j < 4; ++j)
          acc[i][j] += a[i] * b[j];
    }
    __syncthreads();
  }
  #pragma unroll
  for (int i = 0; i < 4; ++i){
    int row = m0 + ty*4 + i;
    if (row < N_NODES){
      #pragma unroll
      for (int j = 0; j < 4; ++j){
        int col = tx*4 + j;
        allemb[(size_t)row * HID + col] += acc[i][j] + linb[col];
      }
    }
  }
}

// ---------------- final row L2 normalize ----------------
__global__ __launch_bounds__(256) void k_norm(const float* __restrict__ allemb, float* __restrict__ out){
  int node = blockIdx.x * 4 + (threadIdx.x >> 6);
  int lane = threadIdx.x & 63;
  float v = allemb[(size_t)node * HID + lane];
  float ss = v * v;
  for (int m = 1; m < 64; m <<= 1) ss += __shfl_xor(ss, m, 64);
  out[(size_t)node * HID + lane] = v / sqrtf(ss);
}

extern "C" void kernel_launch(void* const* d_in, const int* in_sizes, int n_in,
                              void* d_out, int out_size, void* d_ws, size_t ws_size,
                              hipStream_t stream){
  const float* sppmi   = (const float*)d_in[0];   // [3][50000][128]
  const float* W       = (const float*)d_in[1];   // [3][256][128]
  const float* att_src = (const float*)d_in[2];   // [3][256]
  const float* att_dst = (const float*)d_in[3];   // [3][256]
  const float* bias    = (const float*)d_in[4];   // [3][256]
  const float* bn_g    = (const float*)d_in[5];
  const float* bn_b    = (const float*)d_in[6];
  const float* bn_m    = (const float*)d_in[7];
  const float* bn_v    = (const float*)d_in[8];
  const float* lin_W   = (const float*)d_in[9];   // [3][64][256]
  const float* lin_b   = (const float*)d_in[10];  // [3][64]
  const int*   ei      = (const int*)d_in[11];    // [2][800000]

  char* ws = (char*)d_ws;
  size_t off = 0;
  auto alloc = [&](size_t bytes)->char*{ char* p = ws + off; off += (bytes + 255) & ~(size_t)255; return p; };
  float* xw     = (float*)alloc((size_t)N_NODES * HF * 4);
  float* outb   = (float*)alloc((size_t)N_NODES * HF * 4);
  float* as_    = (float*)alloc((size_t)N_NODES * 4 * 4);
  float* ad_    = (float*)alloc((size_t)N_NODES * 4 * 4);
  float* allemb = (float*)alloc((size_t)N_NODES * HID * 4);
  int* counts   = (int*)alloc((size_t)N_NODES * 4);
  int* row_ptr  = (int*)alloc((size_t)(N_NODES + 4) * 4);
  int* cursor   = (int*)alloc((size_t)N_NODES * 4);
  int* csr      = (int*)alloc((size_t)ET * 4);
  int* bsums    = (int*)alloc((size_t)NSCAN_BLK * 4);
  int* bexcl    = (int*)alloc((size_t)NSCAN_BLK * 4);

  hipMemsetAsync(counts, 0, (size_t)N_NODES * 4, stream);
  hipMemsetAsync(allemb, 0, (size_t)N_NODES * HID * 4, stream);

  k_hist<<<(ET + 255) / 256, 256, 0, stream>>>(ei, counts);
  k_bsum<<<NSCAN_BLK, 256, 0, stream>>>(counts, bsums);
  k_bscan<<<1, 256, 0, stream>>>(bsums, bexcl, row_ptr);
  k_sfinal<<<NSCAN_BLK, 256, 0, stream>>>(counts, bexcl, row_ptr, cursor);
  k_scatter<<<(ET + 255) / 256, 256, 0, stream>>>(ei, cursor, csr);

  for (int i = 0; i < 3; ++i){
    k_gemm1<<<dim3(782, 4), 256, 0, stream>>>(sppmi + (size_t)i * N_NODES * IN_F,
                                              W + (size_t)i * HF * IN_F, xw);
    k_alpha<<<12500, 256, 0, stream>>>(xw, att_src + i * 256, att_dst + i * 256, as_, ad_);
    k_agg<<<12500, 256, 0, stream>>>(xw, as_, ad_, row_ptr, csr, bias + i * 256, outb);
    k_gemm2<<<782, 256, 0, stream>>>(outb, lin_W + (size_t)i * HID * HF,
                                     bn_m + i * 256, bn_v + i * 256, bn_g + i * 256, bn_b + i * 256,
                                     lin_b + i * 64, allemb);
  }
  k_norm<<<12500, 256, 0, stream>>>(allemb, (float*)d_out);
}

// Round 3
// 585.420 us; speedup vs baseline: 1.5680x; 1.3571x over previous
//
#include <hip/hip_runtime.h>
#include <hip/hip_bf16.h>

#define N_NODES 50000
#define E0      800000
#define ET      850000   // E0 + N_NODES self-loops
#define IN_F    128
#define HF      256
#define HID     64
#define NEG     0.2f
#define BN_EPSC 1e-5f
#define NSCAN_BLK 196    // ceil(50000/256)

typedef __attribute__((ext_vector_type(8))) short bh8;   // 8 bf16 (4 VGPRs)
typedef __attribute__((ext_vector_type(4))) float fl4;   // 4 f32 accum

__device__ __forceinline__ float lrelu(float x){ return x > 0.f ? x : NEG * x; }
__device__ __forceinline__ unsigned short f2b(float f){
  unsigned int x = __float_as_uint(f);
  unsigned int r = x + 0x7FFF + ((x >> 16) & 1);   // RNE
  return (unsigned short)(r >> 16);
}
__device__ __forceinline__ float b2f(unsigned short u){
  return __uint_as_float((unsigned int)u << 16);
}

// ---------------- fp32 -> bf16 conversion (vectorized) ----------------
__global__ __launch_bounds__(256) void k_cvt(const float* __restrict__ in,
                                             unsigned short* __restrict__ out, int n4){
  int i = blockIdx.x * 256 + threadIdx.x;
  int stride = gridDim.x * 256;
  for (; i < n4; i += stride){
    float4 v = ((const float4*)in)[i];
    ushort4 o;
    o.x = f2b(v.x); o.y = f2b(v.y); o.z = f2b(v.z); o.w = f2b(v.w);
    ((ushort4*)out)[i] = o;
  }
}

// ---------------- CSR build (dst-sorted edge list, shared by all instances) ----------------
__global__ void k_hist(const int* __restrict__ ei, int* __restrict__ counts){
  int e = blockIdx.x * 256 + threadIdx.x;
  if (e >= ET) return;
  int d = (e < E0) ? ei[E0 + e] : (e - E0);
  atomicAdd(&counts[d], 1);
}

__global__ __launch_bounds__(256) void k_bsum(const int* __restrict__ counts, int* __restrict__ bsums){
  int b = blockIdx.x;
  int t = threadIdx.x;
  int idx = b * 256 + t;
  int v = (idx < N_NODES) ? counts[idx] : 0;
  for (int m = 1; m < 64; m <<= 1) v += __shfl_xor(v, m, 64);
  __shared__ int ws[4];
  int lane = t & 63, w = t >> 6;
  if (lane == 0) ws[w] = v;
  __syncthreads();
  if (t == 0) bsums[b] = ws[0] + ws[1] + ws[2] + ws[3];
}

__global__ __launch_bounds__(256) void k_bscan(const int* __restrict__ bsums, int* __restrict__ bexcl,
                                               int* __restrict__ row_ptr){
  int t = threadIdx.x;
  int v = (t < NSCAN_BLK) ? bsums[t] : 0;
  int lane = t & 63, w = t >> 6;
  int incl = v;
  for (int m = 1; m < 64; m <<= 1){
    int n = __shfl_up(incl, m, 64);
    if (lane >= m) incl += n;
  }
  __shared__ int ws[4];
  if (lane == 63) ws[w] = incl;
  __syncthreads();
  if (t == 0){
    int r = 0;
    for (int j = 0; j < 4; ++j){ int x = ws[j]; ws[j] = r; r += x; }
  }
  __syncthreads();
  int excl = incl - v + ws[w];
  if (t < NSCAN_BLK) bexcl[t] = excl;
  if (t == 255) row_ptr[N_NODES] = excl + v;
}

__global__ __launch_bounds__(256) void k_sfinal(const int* __restrict__ counts,
                                                const int* __restrict__ bexcl,
                                                int* __restrict__ row_ptr, int* __restrict__ cursor){
  int b = blockIdx.x;
  int t = threadIdx.x;
  int idx = b * 256 + t;
  int v = (idx < N_NODES) ? counts[idx] : 0;
  int lane = t & 63, w = t >> 6;
  int incl = v;
  for (int m = 1; m < 64; m <<= 1){
    int n = __shfl_up(incl, m, 64);
    if (lane >= m) incl += n;
  }
  __shared__ int ws[4];
  if (lane == 63) ws[w] = incl;
  __syncthreads();
  if (t == 0){
    int r = 0;
    for (int j = 0; j < 4; ++j){ int x = ws[j]; ws[j] = r; r += x; }
  }
  __syncthreads();
  int excl = incl - v + ws[w];
  int pos = bexcl[b] + excl;
  if (idx < N_NODES){ row_ptr[idx] = pos; cursor[idx] = pos; }
}

__global__ void k_scatter(const int* __restrict__ ei, int* __restrict__ cursor,
                          int* __restrict__ csr_src){
  int e = blockIdx.x * 256 + threadIdx.x;
  if (e >= ET) return;
  int s, d;
  if (e < E0){ s = ei[e]; d = ei[E0 + e]; } else { s = e - E0; d = s; }
  int pos = atomicAdd(&cursor[d], 1);
  csr_src[pos] = s;
}

// ---------------- GEMM1 (bf16 MFMA): xwb[N,256] = xb[N,128] @ wb[256,128]^T ----------------
// Tile 128x64, whole K=128 in one pass. 4 waves (2x2), wave tile 64x32.
__global__ __launch_bounds__(256) void k_gemm1(const unsigned short* __restrict__ xb,
                                               const unsigned short* __restrict__ wb,
                                               unsigned short* __restrict__ xwb){
  __shared__ unsigned char Asm[128 * 256];   // 128 rows x 256B (128 bf16), XOR-swizzled
  __shared__ unsigned char Bsm[64 * 256];    // 64 rows x 256B
  int tid = threadIdx.x;
  int m0 = blockIdx.x * 128;
  int n0 = blockIdx.y * 64;

  // stage A: 32KB = 256 thr x 8 x 16B chunks (linear global, swizzled LDS write)
  #pragma unroll
  for (int i = 0; i < 8; ++i){
    int idx = i * 256 + tid;          // 16B units
    int row = idx >> 4;
    int colb = (idx & 15) * 16;
    int grow = m0 + row; if (grow >= N_NODES) grow = N_NODES - 1;
    uint4 v = *(const uint4*)((const char*)xb + (size_t)grow * 256 + colb);
    *(uint4*)(Asm + row * 256 + (colb ^ ((row & 7) << 4))) = v;
  }
  // stage B: 16KB = 256 thr x 4 x 16B
  #pragma unroll
  for (int i = 0; i < 4; ++i){
    int idx = i * 256 + tid;
    int row = idx >> 4;
    int colb = (idx & 15) * 16;
    uint4 v = *(const uint4*)((const char*)wb + (size_t)(n0 + row) * 256 + colb);
    *(uint4*)(Bsm + row * 256 + (colb ^ ((row & 7) << 4))) = v;
  }
  __syncthreads();

  int w = tid >> 6, lane = tid & 63;
  int wr = w >> 1, wc = w & 1;
  int l15 = lane & 15, l4 = lane >> 4;
  fl4 acc[4][2] = {};
  #pragma unroll
  for (int kk = 0; kk < 4; ++kk){
    bh8 af[4];
    #pragma unroll
    for (int m = 0; m < 4; ++m){
      int ar = wr * 64 + m * 16 + l15;
      int ac = (kk * 64 + l4 * 16) ^ ((ar & 7) << 4);
      af[m] = *(const bh8*)(Asm + ar * 256 + ac);
    }
    bh8 bfv[2];
    #pragma unroll
    for (int n = 0; n < 2; ++n){
      int br = wc * 32 + n * 16 + l15;
      int bc = (kk * 64 + l4 * 16) ^ ((br & 7) << 4);
      bfv[n] = *(const bh8*)(Bsm + br * 256 + bc);
    }
    #pragma unroll
    for (int m = 0; m < 4; ++m)
      #pragma unroll
      for (int n = 0; n < 2; ++n)
        acc[m][n] = __builtin_amdgcn_mfma_f32_16x16x32_bf16(af[m], bfv[n], acc[m][n], 0, 0, 0);
  }
  // epilogue: C layout row=(lane>>4)*4+j, col=lane&15
  #pragma unroll
  for (int m = 0; m < 4; ++m){
    int grow0 = m0 + wr * 64 + m * 16 + l4 * 4;
    #pragma unroll
    for (int j = 0; j < 4; ++j){
      int grow = grow0 + j;
      if (grow < N_NODES){
        #pragma unroll
        for (int n = 0; n < 2; ++n){
          int gcol = n0 + wc * 32 + n * 16 + l15;
          xwb[(size_t)grow * HF + gcol] = f2b(acc[m][n][j]);
        }
      }
    }
  }
}

// ---------------- alpha_src / alpha_dst from bf16 xw ----------------
__global__ __launch_bounds__(256) void k_alpha(const unsigned short* __restrict__ xwb,
                       const float* __restrict__ asrc, const float* __restrict__ adst,
                       float* __restrict__ as_, float* __restrict__ ad_){
  int node = blockIdx.x * 4 + (threadIdx.x >> 6);
  int lane = threadIdx.x & 63;
  ushort4 u = *(const ushort4*)&xwb[(size_t)node * HF + lane * 4];
  float vx = b2f(u.x), vy = b2f(u.y), vz = b2f(u.z), vw = b2f(u.w);
  float4 a = *(const float4*)&asrc[lane * 4];
  float4 b = *(const float4*)&adst[lane * 4];
  float ts = vx * a.x + vy * a.y + vz * a.z + vw * a.w;
  float td = vx * b.x + vy * b.y + vz * b.z + vw * b.w;
  for (int m = 1; m < 16; m <<= 1){ ts += __shfl_xor(ts, m, 64); td += __shfl_xor(td, m, 64); }
  if ((lane & 15) == 0){ int h = lane >> 4; as_[node * 4 + h] = ts; ad_[node * 4 + h] = td; }
}

// ---------------- aggregation: segment softmax + bf16 weighted gather ----------------
__global__ __launch_bounds__(256) void k_agg(const unsigned short* __restrict__ xwb,
                     const float* __restrict__ as_, const float* __restrict__ ad_,
                     const int* __restrict__ row_ptr, const int* __restrict__ csr_src,
                     const float* __restrict__ bias, float* __restrict__ outb){
  int node = blockIdx.x * 4 + (threadIdx.x >> 6);
  int lane = threadIdx.x & 63;
  int row0 = row_ptr[node], row1 = row_ptr[node + 1];
  int deg = row1 - row0;
  float4 ad4 = *(const float4*)&ad_[node * 4];
  float m0 = -1e30f, m1 = -1e30f, m2 = -1e30f, m3 = -1e30f;
  for (int j = lane; j < deg; j += 64){
    int s = csr_src[row0 + j];
    float4 a4 = *(const float4*)&as_[s * 4];
    m0 = fmaxf(m0, lrelu(a4.x + ad4.x));
    m1 = fmaxf(m1, lrelu(a4.y + ad4.y));
    m2 = fmaxf(m2, lrelu(a4.z + ad4.z));
    m3 = fmaxf(m3, lrelu(a4.w + ad4.w));
  }
  for (int m = 1; m < 64; m <<= 1){
    m0 = fmaxf(m0, __shfl_xor(m0, m, 64));
    m1 = fmaxf(m1, __shfl_xor(m1, m, 64));
    m2 = fmaxf(m2, __shfl_xor(m2, m, 64));
    m3 = fmaxf(m3, __shfl_xor(m3, m, 64));
  }
  float s0 = 0.f, s1 = 0.f, s2 = 0.f, s3 = 0.f;
  for (int j = lane; j < deg; j += 64){
    int s = csr_src[row0 + j];
    float4 a4 = *(const float4*)&as_[s * 4];
    s0 += __expf(lrelu(a4.x + ad4.x) - m0);
    s1 += __expf(lrelu(a4.y + ad4.y) - m1);
    s2 += __expf(lrelu(a4.z + ad4.z) - m2);
    s3 += __expf(lrelu(a4.w + ad4.w) - m3);
  }
  for (int m = 1; m < 64; m <<= 1){
    s0 += __shfl_xor(s0, m, 64);
    s1 += __shfl_xor(s1, m, 64);
    s2 += __shfl_xor(s2, m, 64);
    s3 += __shfl_xor(s3, m, 64);
  }
  int h = lane >> 4;
  float mh  = (h == 0) ? m0 : (h == 1) ? m1 : (h == 2) ? m2 : m3;
  float sh  = (h == 0) ? s0 : (h == 1) ? s1 : (h == 2) ? s2 : s3;
  float adh = (h == 0) ? ad4.x : (h == 1) ? ad4.y : (h == 2) ? ad4.z : ad4.w;
  float invh = 1.f / (sh + 1e-16f);
  float accx = 0.f, accy = 0.f, accz = 0.f, accw = 0.f;
  for (int jb = 0; jb < deg; jb += 64){
    int sreg = (jb + lane < deg) ? csr_src[row0 + jb + lane] : 0;
    int lim = min(64, deg - jb);
    for (int q = 0; q < lim; ++q){
      int s = __shfl(sreg, q, 64);
      float asv = as_[s * 4 + h];
      float wgt = __expf(lrelu(asv + adh) - mh) * invh;
      ushort4 u = *(const ushort4*)&xwb[(size_t)s * HF + lane * 4];
      accx += wgt * b2f(u.x); accy += wgt * b2f(u.y);
      accz += wgt * b2f(u.z); accw += wgt * b2f(u.w);
    }
  }
  float4 b4 = *(const float4*)&bias[lane * 4];
  float4 o = make_float4(accx + b4.x, accy + b4.y, accz + b4.z, accw + b4.w);
  *(float4*)&outb[(size_t)node * HF + lane * 4] = o;
}

// ---------------- GEMM2: allemb[N,64] += BNReLU(outb)[N,256] @ linW[64,256]^T + linb ----------------
__global__ __launch_bounds__(256) void k_gemm2(const float* __restrict__ A,
                     const float* __restrict__ B,
                     const float* __restrict__ mean, const float* __restrict__ var,
                     const float* __restrict__ gamma, const float* __restrict__ beta,
                     const float* __restrict__ linb, float* __restrict__ allemb){
  __shared__ float As[16][68];
  __shared__ float Bs[16][68];
  int m0 = blockIdx.x * 64;
  int tid = threadIdx.x;
  int tx = tid & 15, ty = tid >> 4;
  int lr = tid >> 2, lk = tid & 3;
  float acc[4][4] = {};
  for (int kc = 0; kc < HF; kc += 16){
    int kb = kc + lk * 4;
    float4 av = make_float4(0.f, 0.f, 0.f, 0.f);
    if (m0 + lr < N_NODES) av = *(const float4*)&A[(size_t)(m0 + lr) * HF + kb];
    float4 mn = *(const float4*)&mean[kb];
    float4 vr = *(const float4*)&var[kb];
    float4 gm = *(const float4*)&gamma[kb];
    float4 bt = *(const float4*)&beta[kb];
    float4 y;
    y.x = fmaxf(0.f, (av.x - mn.x) * (gm.x * rsqrtf(vr.x + BN_EPSC)) + bt.x);
    y.y = fmaxf(0.f, (av.y - mn.y) * (gm.y * rsqrtf(vr.y + BN_EPSC)) + bt.y);
    y.z = fmaxf(0.f, (av.z - mn.z) * (gm.z * rsqrtf(vr.z + BN_EPSC)) + bt.z);
    y.w = fmaxf(0.f, (av.w - mn.w) * (gm.w * rsqrtf(vr.w + BN_EPSC)) + bt.w);
    float4 bv = *(const float4*)&B[(size_t)lr * HF + kb];
    As[lk*4+0][lr]=y.x; As[lk*4+1][lr]=y.y; As[lk*4+2][lr]=y.z; As[lk*4+3][lr]=y.w;
    Bs[lk*4+0][lr]=bv.x; Bs[lk*4+1][lr]=bv.y; Bs[lk*4+2][lr]=bv.z; Bs[lk*4+3][lr]=bv.w;
    __syncthreads();
    #pragma unroll
    for (int kkk = 0; kkk < 16; ++kkk){
      float a[4], b[4];
      *(float4*)a = *(const float4*)&As[kkk][ty * 4];
      *(float4*)b = *(const float4*)&Bs[kkk][tx * 4];
      #pragma unroll
      for (int i = 0; i < 4; ++i)
        #pragma unroll
        for (int j = 0; j < 4; ++j)
          acc[i][j] += a[i] * b[j];
    }
    __syncthreads();
  }
  #pragma unroll
  for (int i = 0; i < 4; ++i){
    int row = m0 + ty * 4 + i;
    if (row < N_NODES){
      #pragma unroll
      for (int j = 0; j < 4; ++j){
        int col = tx * 4 + j;
        allemb[(size_t)row * HID + col] += acc[i][j] + linb[col];
      }
    }
  }
}

// ---------------- final row L2 normalize ----------------
__global__ __launch_bounds__(256) void k_norm(const float* __restrict__ allemb, float* __restrict__ out){
  int node = blockIdx.x * 4 + (threadIdx.x >> 6);
  int lane = threadIdx.x & 63;
  float v = allemb[(size_t)node * HID + lane];
  float ss = v * v;
  for (int m = 1; m < 64; m <<= 1) ss += __shfl_xor(ss, m, 64);
  out[(size_t)node * HID + lane] = v / sqrtf(ss);
}

extern "C" void kernel_launch(void* const* d_in, const int* in_sizes, int n_in,
                              void* d_out, int out_size, void* d_ws, size_t ws_size,
                              hipStream_t stream){
  const float* sppmi   = (const float*)d_in[0];   // [3][50000][128]
  const float* W       = (const float*)d_in[1];   // [3][256][128]
  const float* att_src = (const float*)d_in[2];   // [3][256]
  const float* att_dst = (const float*)d_in[3];   // [3][256]
  const float* bias    = (const float*)d_in[4];   // [3][256]
  const float* bn_g    = (const float*)d_in[5];
  const float* bn_b    = (const float*)d_in[6];
  const float* bn_m    = (const float*)d_in[7];
  const float* bn_v    = (const float*)d_in[8];
  const float* lin_W   = (const float*)d_in[9];   // [3][64][256]
  const float* lin_b   = (const float*)d_in[10];  // [3][64]
  const int*   ei      = (const int*)d_in[11];    // [2][800000]

  char* ws = (char*)d_ws;
  size_t off = 0;
  auto alloc = [&](size_t bytes)->char*{ char* p = ws + off; off += (bytes + 255) & ~(size_t)255; return p; };
  unsigned short* xb   = (unsigned short*)alloc((size_t)3 * N_NODES * IN_F * 2);  // bf16 sppmi
  unsigned short* wb   = (unsigned short*)alloc((size_t)3 * HF * IN_F * 2);       // bf16 W
  unsigned short* xwb  = (unsigned short*)alloc((size_t)N_NODES * HF * 2);        // bf16 xw
  float* outb   = (float*)alloc((size_t)N_NODES * HF * 4);
  float* as_    = (float*)alloc((size_t)N_NODES * 4 * 4);
  float* ad_    = (float*)alloc((size_t)N_NODES * 4 * 4);
  float* allemb = (float*)alloc((size_t)N_NODES * HID * 4);
  int* counts   = (int*)alloc((size_t)N_NODES * 4);
  int* row_ptr  = (int*)alloc((size_t)(N_NODES + 4) * 4);
  int* cursor   = (int*)alloc((size_t)N_NODES * 4);
  int* csr      = (int*)alloc((size_t)ET * 4);
  int* bsums    = (int*)alloc((size_t)NSCAN_BLK * 4);
  int* bexcl    = (int*)alloc((size_t)NSCAN_BLK * 4);

  hipMemsetAsync(counts, 0, (size_t)N_NODES * 4, stream);
  hipMemsetAsync(allemb, 0, (size_t)N_NODES * HID * 4, stream);

  k_cvt<<<2048, 256, 0, stream>>>(sppmi, xb, 3 * N_NODES * IN_F / 4);
  k_cvt<<<96, 256, 0, stream>>>(W, wb, 3 * HF * IN_F / 4);

  k_hist<<<(ET + 255) / 256, 256, 0, stream>>>(ei, counts);
  k_bsum<<<NSCAN_BLK, 256, 0, stream>>>(counts, bsums);
  k_bscan<<<1, 256, 0, stream>>>(bsums, bexcl, row_ptr);
  k_sfinal<<<NSCAN_BLK, 256, 0, stream>>>(counts, bexcl, row_ptr, cursor);
  k_scatter<<<(ET + 255) / 256, 256, 0, stream>>>(ei, cursor, csr);

  for (int i = 0; i < 3; ++i){
    k_gemm1<<<dim3(391, 4), 256, 0, stream>>>(xb + (size_t)i * N_NODES * IN_F,
                                              wb + (size_t)i * HF * IN_F, xwb);
    k_alpha<<<12500, 256, 0, stream>>>(xwb, att_src + i * 256, att_dst + i * 256, as_, ad_);
    k_agg<<<12500, 256, 0, stream>>>(xwb, as_, ad_, row_ptr, csr, bias + i * 256, outb);
    k_gemm2<<<782, 256, 0, stream>>>(outb, lin_W + (size_t)i * HID * HF,
                                     bn_m + i * 256, bn_v + i * 256, bn_g + i * 256, bn_b + i * 256,
                                     lin_b + i * 64, allemb);
  }
  k_norm<<<12500, 256, 0, stream>>>(allemb, (float*)d_out);
}

// Round 4
// 513.299 us; speedup vs baseline: 1.7883x; 1.1405x over previous
//
#include <hip/hip_runtime.h>
#include <hip/hip_bf16.h>

#define N_NODES 50000
#define E0      800000
#define ET      850000   // E0 + N_NODES self-loops
#define IN_F    128
#define HF      256
#define HID     64
#define NEG     0.2f
#define BN_EPSC 1e-5f
#define NSCAN_BLK 196    // ceil(50000/256)

typedef __attribute__((ext_vector_type(8))) short bh8;   // 8 bf16 (4 VGPRs)
typedef __attribute__((ext_vector_type(4))) float fl4;   // 4 f32 accum

__device__ __forceinline__ float lrelu(float x){ return x > 0.f ? x : NEG * x; }
__device__ __forceinline__ unsigned short f2b(float f){
  unsigned int x = __float_as_uint(f);
  unsigned int r = x + 0x7FFF + ((x >> 16) & 1);   // RNE
  return (unsigned short)(r >> 16);
}
__device__ __forceinline__ float b2f(unsigned short u){
  return __uint_as_float((unsigned int)u << 16);
}

// ---------------- fp32 -> bf16 conversion (vectorized) ----------------
__global__ __launch_bounds__(256) void k_cvt(const float* __restrict__ in,
                                             unsigned short* __restrict__ out, int n4){
  int i = blockIdx.x * 256 + threadIdx.x;
  int stride = gridDim.x * 256;
  for (; i < n4; i += stride){
    float4 v = ((const float4*)in)[i];
    ushort4 o;
    o.x = f2b(v.x); o.y = f2b(v.y); o.z = f2b(v.z); o.w = f2b(v.w);
    ((ushort4*)out)[i] = o;
  }
}

// ---------------- CSR build ----------------
__global__ void k_hist(const int* __restrict__ ei, int* __restrict__ counts){
  int e = blockIdx.x * 256 + threadIdx.x;
  if (e >= ET) return;
  int d = (e < E0) ? ei[E0 + e] : (e - E0);
  atomicAdd(&counts[d], 1);
}

__global__ __launch_bounds__(256) void k_bsum(const int* __restrict__ counts, int* __restrict__ bsums){
  int b = blockIdx.x;
  int t = threadIdx.x;
  int idx = b * 256 + t;
  int v = (idx < N_NODES) ? counts[idx] : 0;
  for (int m = 1; m < 64; m <<= 1) v += __shfl_xor(v, m, 64);
  __shared__ int ws[4];
  int lane = t & 63, w = t >> 6;
  if (lane == 0) ws[w] = v;
  __syncthreads();
  if (t == 0) bsums[b] = ws[0] + ws[1] + ws[2] + ws[3];
}

__global__ __launch_bounds__(256) void k_bscan(const int* __restrict__ bsums, int* __restrict__ bexcl,
                                               int* __restrict__ row_ptr){
  int t = threadIdx.x;
  int v = (t < NSCAN_BLK) ? bsums[t] : 0;
  int lane = t & 63, w = t >> 6;
  int incl = v;
  for (int m = 1; m < 64; m <<= 1){
    int n = __shfl_up(incl, m, 64);
    if (lane >= m) incl += n;
  }
  __shared__ int ws[4];
  if (lane == 63) ws[w] = incl;
  __syncthreads();
  if (t == 0){
    int r = 0;
    for (int j = 0; j < 4; ++j){ int x = ws[j]; ws[j] = r; r += x; }
  }
  __syncthreads();
  int excl = incl - v + ws[w];
  if (t < NSCAN_BLK) bexcl[t] = excl;
  if (t == 255) row_ptr[N_NODES] = excl + v;
}

__global__ __launch_bounds__(256) void k_sfinal(const int* __restrict__ counts,
                                                const int* __restrict__ bexcl,
                                                int* __restrict__ row_ptr, int* __restrict__ cursor){
  int b = blockIdx.x;
  int t = threadIdx.x;
  int idx = b * 256 + t;
  int v = (idx < N_NODES) ? counts[idx] : 0;
  int lane = t & 63, w = t >> 6;
  int incl = v;
  for (int m = 1; m < 64; m <<= 1){
    int n = __shfl_up(incl, m, 64);
    if (lane >= m) incl += n;
  }
  __shared__ int ws[4];
  if (lane == 63) ws[w] = incl;
  __syncthreads();
  if (t == 0){
    int r = 0;
    for (int j = 0; j < 4; ++j){ int x = ws[j]; ws[j] = r; r += x; }
  }
  __syncthreads();
  int excl = incl - v + ws[w];
  int pos = bexcl[b] + excl;
  if (idx < N_NODES){ row_ptr[idx] = pos; cursor[idx] = pos; }
}

__global__ void k_scatter(const int* __restrict__ ei, int* __restrict__ cursor,
                          int* __restrict__ csr_src){
  int e = blockIdx.x * 256 + threadIdx.x;
  if (e >= ET) return;
  int s, d;
  if (e < E0){ s = ei[e]; d = ei[E0 + e]; } else { s = e - E0; d = s; }
  int pos = atomicAdd(&cursor[d], 1);
  csr_src[pos] = s;
}

// ---------------- GEMM1 (bf16 MFMA): xwb[N,256] = xb[N,128] @ wb[256,128]^T ----------------
__global__ __launch_bounds__(256) void k_gemm1(const unsigned short* __restrict__ xb,
                                               const unsigned short* __restrict__ wb,
                                               unsigned short* __restrict__ xwb){
  __shared__ unsigned char Asm[128 * 256];
  __shared__ unsigned char Bsm[64 * 256];
  int tid = threadIdx.x;
  int m0 = blockIdx.x * 128;
  int n0 = blockIdx.y * 64;

  #pragma unroll
  for (int i = 0; i < 8; ++i){
    int idx = i * 256 + tid;
    int row = idx >> 4;
    int colb = (idx & 15) * 16;
    int grow = m0 + row; if (grow >= N_NODES) grow = N_NODES - 1;
    uint4 v = *(const uint4*)((const char*)xb + (size_t)grow * 256 + colb);
    *(uint4*)(Asm + row * 256 + (colb ^ ((row & 7) << 4))) = v;
  }
  #pragma unroll
  for (int i = 0; i < 4; ++i){
    int idx = i * 256 + tid;
    int row = idx >> 4;
    int colb = (idx & 15) * 16;
    uint4 v = *(const uint4*)((const char*)wb + (size_t)(n0 + row) * 256 + colb);
    *(uint4*)(Bsm + row * 256 + (colb ^ ((row & 7) << 4))) = v;
  }
  __syncthreads();

  int w = tid >> 6, lane = tid & 63;
  int wr = w >> 1, wc = w & 1;
  int l15 = lane & 15, l4 = lane >> 4;
  fl4 acc[4][2] = {};
  #pragma unroll
  for (int kk = 0; kk < 4; ++kk){
    bh8 af[4];
    #pragma unroll
    for (int m = 0; m < 4; ++m){
      int ar = wr * 64 + m * 16 + l15;
      int ac = (kk * 64 + l4 * 16) ^ ((ar & 7) << 4);
      af[m] = *(const bh8*)(Asm + ar * 256 + ac);
    }
    bh8 bfv[2];
    #pragma unroll
    for (int n = 0; n < 2; ++n){
      int br = wc * 32 + n * 16 + l15;
      int bc = (kk * 64 + l4 * 16) ^ ((br & 7) << 4);
      bfv[n] = *(const bh8*)(Bsm + br * 256 + bc);
    }
    #pragma unroll
    for (int m = 0; m < 4; ++m)
      #pragma unroll
      for (int n = 0; n < 2; ++n)
        acc[m][n] = __builtin_amdgcn_mfma_f32_16x16x32_bf16(af[m], bfv[n], acc[m][n], 0, 0, 0);
  }
  #pragma unroll
  for (int m = 0; m < 4; ++m){
    int grow0 = m0 + wr * 64 + m * 16 + l4 * 4;
    #pragma unroll
    for (int j = 0; j < 4; ++j){
      int grow = grow0 + j;
      if (grow < N_NODES){
        #pragma unroll
        for (int n = 0; n < 2; ++n){
          int gcol = n0 + wc * 32 + n * 16 + l15;
          xwb[(size_t)grow * HF + gcol] = f2b(acc[m][n][j]);
        }
      }
    }
  }
}

// ---------------- alpha_src / alpha_dst from bf16 xw ----------------
__global__ __launch_bounds__(256) void k_alpha(const unsigned short* __restrict__ xwb,
                       const float* __restrict__ asrc, const float* __restrict__ adst,
                       float* __restrict__ as_, float* __restrict__ ad_){
  int node = blockIdx.x * 4 + (threadIdx.x >> 6);
  int lane = threadIdx.x & 63;
  ushort4 u = *(const ushort4*)&xwb[(size_t)node * HF + lane * 4];
  float vx = b2f(u.x), vy = b2f(u.y), vz = b2f(u.z), vw = b2f(u.w);
  float4 a = *(const float4*)&asrc[lane * 4];
  float4 b = *(const float4*)&adst[lane * 4];
  float ts = vx * a.x + vy * a.y + vz * a.z + vw * a.w;
  float td = vx * b.x + vy * b.y + vz * b.z + vw * b.w;
  for (int m = 1; m < 16; m <<= 1){ ts += __shfl_xor(ts, m, 64); td += __shfl_xor(td, m, 64); }
  if ((lane & 15) == 0){ int h = lane >> 4; as_[node * 4 + h] = ts; ad_[node * 4 + h] = td; }
}

// ---------------- aggregation: single-pass exp (no max; bounded args), LDS broadcast ----------------
__global__ __launch_bounds__(256) void k_agg(const unsigned short* __restrict__ xwb,
                     const float* __restrict__ as_, const float* __restrict__ ad_,
                     const int* __restrict__ row_ptr, const int* __restrict__ csr_src,
                     const float* __restrict__ bias, unsigned short* __restrict__ outb){
  __shared__ float eLds[4][4][65];   // [wave][head][edge-slot], padded -> conflict-free
  __shared__ int   sLds[4][64];
  int w = threadIdx.x >> 6;
  int lane = threadIdx.x & 63;
  int node = blockIdx.x * 4 + w;
  int row0 = row_ptr[node];
  int deg = row_ptr[node + 1] - row0;
  float4 ad4 = *(const float4*)&ad_[node * 4];
  int h = lane >> 4;
  float accx = 0.f, accy = 0.f, accz = 0.f, accw = 0.f;
  float sh;   // softmax denom for my head

  if (deg <= 64){
    int sreg = 0; float e0 = 0.f, e1 = 0.f, e2 = 0.f, e3 = 0.f;
    if (lane < deg){
      sreg = csr_src[row0 + lane];
      float4 a4 = *(const float4*)&as_[sreg * 4];
      e0 = __expf(lrelu(a4.x + ad4.x));
      e1 = __expf(lrelu(a4.y + ad4.y));
      e2 = __expf(lrelu(a4.z + ad4.z));
      e3 = __expf(lrelu(a4.w + ad4.w));
    }
    sLds[w][lane] = sreg;
    eLds[w][0][lane] = e0; eLds[w][1][lane] = e1;
    eLds[w][2][lane] = e2; eLds[w][3][lane] = e3;
    float s0 = e0, s1 = e1, s2 = e2, s3 = e3;
    for (int m = 1; m < 64; m <<= 1){
      s0 += __shfl_xor(s0, m, 64); s1 += __shfl_xor(s1, m, 64);
      s2 += __shfl_xor(s2, m, 64); s3 += __shfl_xor(s3, m, 64);
    }
    sh = (h == 0) ? s0 : (h == 1) ? s1 : (h == 2) ? s2 : s3;
    for (int q = 0; q < deg; ++q){
      int s = sLds[w][q];
      float wh = eLds[w][h][q];
      ushort4 u = *(const ushort4*)&xwb[(size_t)s * HF + lane * 4];
      accx += wh * b2f(u.x); accy += wh * b2f(u.y);
      accz += wh * b2f(u.z); accw += wh * b2f(u.w);
    }
  } else {
    // rare fallback: global denom first, then chunked broadcast
    float s0 = 0.f, s1 = 0.f, s2 = 0.f, s3 = 0.f;
    for (int j = lane; j < deg; j += 64){
      int s = csr_src[row0 + j];
      float4 a4 = *(const float4*)&as_[s * 4];
      s0 += __expf(lrelu(a4.x + ad4.x));
      s1 += __expf(lrelu(a4.y + ad4.y));
      s2 += __expf(lrelu(a4.z + ad4.z));
      s3 += __expf(lrelu(a4.w + ad4.w));
    }
    for (int m = 1; m < 64; m <<= 1){
      s0 += __shfl_xor(s0, m, 64); s1 += __shfl_xor(s1, m, 64);
      s2 += __shfl_xor(s2, m, 64); s3 += __shfl_xor(s3, m, 64);
    }
    sh = (h == 0) ? s0 : (h == 1) ? s1 : (h == 2) ? s2 : s3;
    for (int jb = 0; jb < deg; jb += 64){
      int jj = jb + lane;
      int sreg = 0; float e0 = 0.f, e1 = 0.f, e2 = 0.f, e3 = 0.f;
      if (jj < deg){
        sreg = csr_src[row0 + jj];
        float4 a4 = *(const float4*)&as_[sreg * 4];
        e0 = __expf(lrelu(a4.x + ad4.x));
        e1 = __expf(lrelu(a4.y + ad4.y));
        e2 = __expf(lrelu(a4.z + ad4.z));
        e3 = __expf(lrelu(a4.w + ad4.w));
      }
      sLds[w][lane] = sreg;
      eLds[w][0][lane] = e0; eLds[w][1][lane] = e1;
      eLds[w][2][lane] = e2; eLds[w][3][lane] = e3;
      __builtin_amdgcn_s_waitcnt(0);   // drain lgkm before re-reading own slots
      int lim = min(64, deg - jb);
      for (int q = 0; q < lim; ++q){
        int s = sLds[w][q];
        float wh = eLds[w][h][q];
        ushort4 u = *(const ushort4*)&xwb[(size_t)s * HF + lane * 4];
        accx += wh * b2f(u.x); accy += wh * b2f(u.y);
        accz += wh * b2f(u.z); accw += wh * b2f(u.w);
      }
    }
  }
  float invh = 1.f / (sh + 1e-16f);
  float4 b4 = *(const float4*)&bias[lane * 4];
  ushort4 o;
  o.x = f2b(accx * invh + b4.x); o.y = f2b(accy * invh + b4.y);
  o.z = f2b(accz * invh + b4.z); o.w = f2b(accw * invh + b4.w);
  *(ushort4*)&outb[(size_t)node * HF + lane * 4] = o;
}

// ---------------- GEMM2: allemb[N,64] += BNReLU(outb_bf16)[N,256] @ linW[64,256]^T + linb ----------------
__global__ __launch_bounds__(256) void k_gemm2(const unsigned short* __restrict__ A,
                     const float* __restrict__ B,
                     const float* __restrict__ mean, const float* __restrict__ var,
                     const float* __restrict__ gamma, const float* __restrict__ beta,
                     const float* __restrict__ linb, float* __restrict__ allemb){
  __shared__ float As[16][68];
  __shared__ float Bs[16][68];
  int m0 = blockIdx.x * 64;
  int tid = threadIdx.x;
  int tx = tid & 15, ty = tid >> 4;
  int lr = tid >> 2, lk = tid & 3;
  float acc[4][4] = {};
  for (int kc = 0; kc < HF; kc += 16){
    int kb = kc + lk * 4;
    ushort4 au = make_ushort4(0, 0, 0, 0);
    if (m0 + lr < N_NODES) au = *(const ushort4*)&A[(size_t)(m0 + lr) * HF + kb];
    float4 mn = *(const float4*)&mean[kb];
    float4 vr = *(const float4*)&var[kb];
    float4 gm = *(const float4*)&gamma[kb];
    float4 bt = *(const float4*)&beta[kb];
    float4 y;
    y.x = fmaxf(0.f, (b2f(au.x) - mn.x) * (gm.x * rsqrtf(vr.x + BN_EPSC)) + bt.x);
    y.y = fmaxf(0.f, (b2f(au.y) - mn.y) * (gm.y * rsqrtf(vr.y + BN_EPSC)) + bt.y);
    y.z = fmaxf(0.f, (b2f(au.z) - mn.z) * (gm.z * rsqrtf(vr.z + BN_EPSC)) + bt.z);
    y.w = fmaxf(0.f, (b2f(au.w) - mn.w) * (gm.w * rsqrtf(vr.w + BN_EPSC)) + bt.w);
    float4 bv = *(const float4*)&B[(size_t)lr * HF + kb];
    As[lk*4+0][lr]=y.x; As[lk*4+1][lr]=y.y; As[lk*4+2][lr]=y.z; As[lk*4+3][lr]=y.w;
    Bs[lk*4+0][lr]=bv.x; Bs[lk*4+1][lr]=bv.y; Bs[lk*4+2][lr]=bv.z; Bs[lk*4+3][lr]=bv.w;
    __syncthreads();
    #pragma unroll
    for (int kkk = 0; kkk < 16; ++kkk){
      float a[4], b[4];
      *(float4*)a = *(const float4*)&As[kkk][ty * 4];
      *(float4*)b = *(const float4*)&Bs[kkk][tx * 4];
      #pragma unroll
      for (int i = 0; i < 4; ++i)
        #pragma unroll
        for (int j = 0; j < 4; ++j)
          acc[i][j] += a[i] * b[j];
    }
    __syncthreads();
  }
  #pragma unroll
  for (int i = 0; i < 4; ++i){
    int row = m0 + ty * 4 + i;
    if (row < N_NODES){
      #pragma unroll
      for (int j = 0; j < 4; ++j){
        int col = tx * 4 + j;
        allemb[(size_t)row * HID + col] += acc[i][j] + linb[col];
      }
    }
  }
}

// ---------------- final row L2 normalize ----------------
__global__ __launch_bounds__(256) void k_norm(const float* __restrict__ allemb, float* __restrict__ out){
  int node = blockIdx.x * 4 + (threadIdx.x >> 6);
  int lane = threadIdx.x & 63;
  float v = allemb[(size_t)node * HID + lane];
  float ss = v * v;
  for (int m = 1; m < 64; m <<= 1) ss += __shfl_xor(ss, m, 64);
  out[(size_t)node * HID + lane] = v / sqrtf(ss);
}

extern "C" void kernel_launch(void* const* d_in, const int* in_sizes, int n_in,
                              void* d_out, int out_size, void* d_ws, size_t ws_size,
                              hipStream_t stream){
  const float* sppmi   = (const float*)d_in[0];
  const float* W       = (const float*)d_in[1];
  const float* att_src = (const float*)d_in[2];
  const float* att_dst = (const float*)d_in[3];
  const float* bias    = (const float*)d_in[4];
  const float* bn_g    = (const float*)d_in[5];
  const float* bn_b    = (const float*)d_in[6];
  const float* bn_m    = (const float*)d_in[7];
  const float* bn_v    = (const float*)d_in[8];
  const float* lin_W   = (const float*)d_in[9];
  const float* lin_b   = (const float*)d_in[10];
  const int*   ei      = (const int*)d_in[11];

  char* ws = (char*)d_ws;
  size_t off = 0;
  auto alloc = [&](size_t bytes)->char*{ char* p = ws + off; off += (bytes + 255) & ~(size_t)255; return p; };
  unsigned short* xb   = (unsigned short*)alloc((size_t)3 * N_NODES * IN_F * 2);
  unsigned short* wb   = (unsigned short*)alloc((size_t)3 * HF * IN_F * 2);
  unsigned short* xwb  = (unsigned short*)alloc((size_t)N_NODES * HF * 2);
  unsigned short* outb = (unsigned short*)alloc((size_t)N_NODES * HF * 2);
  float* as_    = (float*)alloc((size_t)N_NODES * 4 * 4);
  float* ad_    = (float*)alloc((size_t)N_NODES * 4 * 4);
  float* allemb = (float*)alloc((size_t)N_NODES * HID * 4);
  int* counts   = (int*)alloc((size_t)N_NODES * 4);
  int* row_ptr  = (int*)alloc((size_t)(N_NODES + 4) * 4);
  int* cursor   = (int*)alloc((size_t)N_NODES * 4);
  int* csr      = (int*)alloc((size_t)ET * 4);
  int* bsums    = (int*)alloc((size_t)NSCAN_BLK * 4);
  int* bexcl    = (int*)alloc((size_t)NSCAN_BLK * 4);

  hipMemsetAsync(counts, 0, (size_t)N_NODES * 4, stream);
  hipMemsetAsync(allemb, 0, (size_t)N_NODES * HID * 4, stream);

  k_cvt<<<2048, 256, 0, stream>>>(sppmi, xb, 3 * N_NODES * IN_F / 4);
  k_cvt<<<96, 256, 0, stream>>>(W, wb, 3 * HF * IN_F / 4);

  k_hist<<<(ET + 255) / 256, 256, 0, stream>>>(ei, counts);
  k_bsum<<<NSCAN_BLK, 256, 0, stream>>>(counts, bsums);
  k_bscan<<<1, 256, 0, stream>>>(bsums, bexcl, row_ptr);
  k_sfinal<<<NSCAN_BLK, 256, 0, stream>>>(counts, bexcl, row_ptr, cursor);
  k_scatter<<<(ET + 255) / 256, 256, 0, stream>>>(ei, cursor, csr);

  for (int i = 0; i < 3; ++i){
    k_gemm1<<<dim3(391, 4), 256, 0, stream>>>(xb + (size_t)i * N_NODES * IN_F,
                                              wb + (size_t)i * HF * IN_F, xwb);
    k_alpha<<<12500, 256, 0, stream>>>(xwb, att_src + i * 256, att_dst + i * 256, as_, ad_);
    k_agg<<<12500, 256, 0, stream>>>(xwb, as_, ad_, row_ptr, csr, bias + i * 256, outb);
    k_gemm2<<<782, 256, 0, stream>>>(outb, lin_W + (size_t)i * HID * HF,
                                     bn_m + i * 256, bn_v + i * 256, bn_g + i * 256, bn_b + i * 256,
                                     lin_b + i * 64, allemb);
  }
  k_norm<<<12500, 256, 0, stream>>>(allemb, (float*)d_out);
}

// Round 5
// 399.238 us; speedup vs baseline: 2.2993x; 1.2857x over previous
//
#include <hip/hip_runtime.h>
#include <hip/hip_bf16.h>

#define N_NODES 50000
#define E0      800000
#define ET      850000   // E0 + N_NODES self-loops
#define IN_F    128
#define HF      256
#define HID     64
#define NEG     0.2f
#define BN_EPSC 1e-5f
#define NSCAN_BLK 196    // ceil(50000/256)

typedef __attribute__((ext_vector_type(8))) short bh8;            // 8 bf16 (4 VGPRs)
typedef __attribute__((ext_vector_type(4))) float fl4;            // 4 f32 accum
typedef __attribute__((ext_vector_type(8))) unsigned short us8;   // 8 u16

__device__ __forceinline__ float lrelu(float x){ return x > 0.f ? x : NEG * x; }
__device__ __forceinline__ unsigned short f2b(float f){
  unsigned int x = __float_as_uint(f);
  unsigned int r = x + 0x7FFF + ((x >> 16) & 1);   // RNE
  return (unsigned short)(r >> 16);
}
__device__ __forceinline__ float b2f(unsigned short u){
  return __uint_as_float((unsigned int)u << 16);
}

// ---------------- fp32 -> bf16 conversion (weights only) ----------------
__global__ __launch_bounds__(256) void k_cvt(const float* __restrict__ in,
                                             unsigned short* __restrict__ out, int n4){
  int i = blockIdx.x * 256 + threadIdx.x;
  int stride = gridDim.x * 256;
  for (; i < n4; i += stride){
    float4 v = ((const float4*)in)[i];
    ushort4 o;
    o.x = f2b(v.x); o.y = f2b(v.y); o.z = f2b(v.z); o.w = f2b(v.w);
    ((ushort4*)out)[i] = o;
  }
}

// ---------------- BN -> scale/shift precompute ----------------
__global__ __launch_bounds__(256) void k_bnprep(const float* __restrict__ g, const float* __restrict__ b,
                                                const float* __restrict__ m, const float* __restrict__ v,
                                                float* __restrict__ scale, float* __restrict__ shiftv){
  int i = blockIdx.x * 256 + threadIdx.x;
  if (i >= 3 * HF) return;
  float s = g[i] * rsqrtf(v[i] + BN_EPSC);
  scale[i] = s;
  shiftv[i] = b[i] - m[i] * s;
}

// ---------------- CSR build ----------------
__global__ void k_hist(const int* __restrict__ ei, int* __restrict__ counts){
  int e = blockIdx.x * 256 + threadIdx.x;
  if (e >= ET) return;
  int d = (e < E0) ? ei[E0 + e] : (e - E0);
  atomicAdd(&counts[d], 1);
}

__global__ __launch_bounds__(256) void k_bsum(const int* __restrict__ counts, int* __restrict__ bsums){
  int b = blockIdx.x;
  int t = threadIdx.x;
  int idx = b * 256 + t;
  int v = (idx < N_NODES) ? counts[idx] : 0;
  for (int m = 1; m < 64; m <<= 1) v += __shfl_xor(v, m, 64);
  __shared__ int ws[4];
  int lane = t & 63, w = t >> 6;
  if (lane == 0) ws[w] = v;
  __syncthreads();
  if (t == 0) bsums[b] = ws[0] + ws[1] + ws[2] + ws[3];
}

__global__ __launch_bounds__(256) void k_bscan(const int* __restrict__ bsums, int* __restrict__ bexcl,
                                               int* __restrict__ row_ptr){
  int t = threadIdx.x;
  int v = (t < NSCAN_BLK) ? bsums[t] : 0;
  int lane = t & 63, w = t >> 6;
  int incl = v;
  for (int m = 1; m < 64; m <<= 1){
    int n = __shfl_up(incl, m, 64);
    if (lane >= m) incl += n;
  }
  __shared__ int ws[4];
  if (lane == 63) ws[w] = incl;
  __syncthreads();
  if (t == 0){
    int r = 0;
    for (int j = 0; j < 4; ++j){ int x = ws[j]; ws[j] = r; r += x; }
  }
  __syncthreads();
  int excl = incl - v + ws[w];
  if (t < NSCAN_BLK) bexcl[t] = excl;
  if (t == 255) row_ptr[N_NODES] = excl + v;
}

__global__ __launch_bounds__(256) void k_sfinal(const int* __restrict__ counts,
                                                const int* __restrict__ bexcl,
                                                int* __restrict__ row_ptr, int* __restrict__ cursor){
  int b = blockIdx.x;
  int t = threadIdx.x;
  int idx = b * 256 + t;
  int v = (idx < N_NODES) ? counts[idx] : 0;
  int lane = t & 63, w = t >> 6;
  int incl = v;
  for (int m = 1; m < 64; m <<= 1){
    int n = __shfl_up(incl, m, 64);
    if (lane >= m) incl += n;
  }
  __shared__ int ws[4];
  if (lane == 63) ws[w] = incl;
  __syncthreads();
  if (t == 0){
    int r = 0;
    for (int j = 0; j < 4; ++j){ int x = ws[j]; ws[j] = r; r += x; }
  }
  __syncthreads();
  int excl = incl - v + ws[w];
  int pos = bexcl[b] + excl;
  if (idx < N_NODES){ row_ptr[idx] = pos; cursor[idx] = pos; }
}

__global__ void k_scatter(const int* __restrict__ ei, int* __restrict__ cursor,
                          int* __restrict__ csr_src){
  int e = blockIdx.x * 256 + threadIdx.x;
  if (e >= ET) return;
  int s, d;
  if (e < E0){ s = ei[e]; d = ei[E0 + e]; } else { s = e - E0; d = s; }
  int pos = atomicAdd(&cursor[d], 1);
  csr_src[pos] = s;
}

// ---------------- GEMM1 fused: f32 A -> bf16 MFMA, epilogue computes xwb + alpha ----------------
// Tile M=32, N=256 (full). 4 waves; wave w == head w (cols 64w..64w+63).
__global__ __launch_bounds__(256) void k_gemm1f(const float* __restrict__ x,
                                                const unsigned short* __restrict__ wbv,
                                                const float* __restrict__ asrc,
                                                const float* __restrict__ adst,
                                                unsigned short* __restrict__ xwb,
                                                float* __restrict__ as_, float* __restrict__ ad_){
  __shared__ unsigned char Asm[32 * 256];    // 8KB  (32 rows x 128 bf16)
  __shared__ unsigned char Bsm[256 * 256];   // 64KB (256 rows x 128 bf16)
  int tid = threadIdx.x;
  int m0 = blockIdx.x * 32;

  // stage A with fused f32->bf16: 1024 float4 chunks
  #pragma unroll
  for (int k = 0; k < 4; ++k){
    int c = k * 256 + tid;
    int row = c >> 5;             // 32 float4 per row
    int c4 = c & 31;
    int grow = m0 + row; if (grow >= N_NODES) grow = N_NODES - 1;
    float4 v = *(const float4*)&x[(size_t)grow * IN_F + c4 * 4];
    ushort4 o = make_ushort4(f2b(v.x), f2b(v.y), f2b(v.z), f2b(v.w));
    int colb = c4 * 8;
    int addr = row * 256 + ((colb & ~15) ^ ((row & 7) << 4)) + (colb & 15);
    *(ushort4*)(Asm + addr) = o;
  }
  // stage B: 4096 16B chunks
  #pragma unroll
  for (int k = 0; k < 16; ++k){
    int c = k * 256 + tid;
    int row = c >> 4;
    int colb = (c & 15) * 16;
    uint4 v = *(const uint4*)((const char*)wbv + (size_t)row * 256 + colb);
    *(uint4*)(Bsm + row * 256 + (colb ^ ((row & 7) << 4))) = v;
  }
  __syncthreads();

  int w = tid >> 6, lane = tid & 63;
  int l15 = lane & 15, l4 = lane >> 4;
  fl4 acc[2][4] = {};
  #pragma unroll
  for (int kk = 0; kk < 4; ++kk){
    bh8 af[2];
    #pragma unroll
    for (int m = 0; m < 2; ++m){
      int ar = m * 16 + l15;
      int ac = (kk * 64 + l4 * 16) ^ ((ar & 7) << 4);
      af[m] = *(const bh8*)(Asm + ar * 256 + ac);
    }
    bh8 bfv[4];
    #pragma unroll
    for (int n = 0; n < 4; ++n){
      int br = w * 64 + n * 16 + l15;
      int bc = (kk * 64 + l4 * 16) ^ ((br & 7) << 4);
      bfv[n] = *(const bh8*)(Bsm + br * 256 + bc);
    }
    #pragma unroll
    for (int m = 0; m < 2; ++m)
      #pragma unroll
      for (int n = 0; n < 4; ++n)
        acc[m][n] = __builtin_amdgcn_mfma_f32_16x16x32_bf16(af[m], bfv[n], acc[m][n], 0, 0, 0);
  }

  float asv[4], adv[4];
  #pragma unroll
  for (int n = 0; n < 4; ++n){
    int c = w * 64 + n * 16 + l15;
    asv[n] = asrc[c]; adv[n] = adst[c];
  }

  #pragma unroll
  for (int m = 0; m < 2; ++m){
    #pragma unroll
    for (int j = 0; j < 4; ++j){
      int grow = m0 + m * 16 + l4 * 4 + j;
      if (grow < N_NODES){
        #pragma unroll
        for (int n = 0; n < 4; ++n)
          xwb[(size_t)grow * HF + w * 64 + n * 16 + l15] = f2b(acc[m][n][j]);
      }
      float ts = acc[m][0][j]*asv[0] + acc[m][1][j]*asv[1] + acc[m][2][j]*asv[2] + acc[m][3][j]*asv[3];
      float td = acc[m][0][j]*adv[0] + acc[m][1][j]*adv[1] + acc[m][2][j]*adv[2] + acc[m][3][j]*adv[3];
      #pragma unroll
      for (int mm = 1; mm < 16; mm <<= 1){ ts += __shfl_xor(ts, mm, 64); td += __shfl_xor(td, mm, 64); }
      if (l15 == 0 && grow < N_NODES){
        as_[grow * 4 + w] = ts;
        ad_[grow * 4 + w] = td;
      }
    }
  }
}

// ---------------- aggregation: single-pass exp + LDS broadcast, 4x-unrolled gather ----------------
__global__ __launch_bounds__(256) void k_agg(const unsigned short* __restrict__ xwb,
                     const float* __restrict__ as_, const float* __restrict__ ad_,
                     const int* __restrict__ row_ptr, const int* __restrict__ csr_src,
                     const float* __restrict__ bias, unsigned short* __restrict__ outb){
  __shared__ float eLds[4][4][65];
  __shared__ int   sLds[4][64];   // byte offsets (src * 512)
  int w = threadIdx.x >> 6;
  int lane = threadIdx.x & 63;
  int node = blockIdx.x * 4 + w;
  int row0 = row_ptr[node];
  int deg = row_ptr[node + 1] - row0;
  float4 ad4 = *(const float4*)&ad_[node * 4];
  int h = lane >> 4;
  float accx = 0.f, accy = 0.f, accz = 0.f, accw = 0.f;
  float sh;
  const char* xwp = (const char*)xwb;
  int lb = lane * 8;

  if (deg <= 64){
    int soff = 0; float e0 = 0.f, e1 = 0.f, e2 = 0.f, e3 = 0.f;
    if (lane < deg){
      int sreg = csr_src[row0 + lane];
      soff = sreg * 512;
      float4 a4 = *(const float4*)&as_[sreg * 4];
      e0 = __expf(lrelu(a4.x + ad4.x));
      e1 = __expf(lrelu(a4.y + ad4.y));
      e2 = __expf(lrelu(a4.z + ad4.z));
      e3 = __expf(lrelu(a4.w + ad4.w));
    }
    sLds[w][lane] = soff;
    eLds[w][0][lane] = e0; eLds[w][1][lane] = e1;
    eLds[w][2][lane] = e2; eLds[w][3][lane] = e3;
    float s0 = e0, s1 = e1, s2 = e2, s3 = e3;
    for (int m = 1; m < 64; m <<= 1){
      s0 += __shfl_xor(s0, m, 64); s1 += __shfl_xor(s1, m, 64);
      s2 += __shfl_xor(s2, m, 64); s3 += __shfl_xor(s3, m, 64);
    }
    sh = (h == 0) ? s0 : (h == 1) ? s1 : (h == 2) ? s2 : s3;
    int q = 0;
    for (; q + 4 <= deg; q += 4){
      int o0 = sLds[w][q],   o1 = sLds[w][q+1];
      int o2 = sLds[w][q+2], o3 = sLds[w][q+3];
      float w0 = eLds[w][h][q],   w1 = eLds[w][h][q+1];
      float w2 = eLds[w][h][q+2], w3 = eLds[w][h][q+3];
      ushort4 u0 = *(const ushort4*)(xwp + o0 + lb);
      ushort4 u1 = *(const ushort4*)(xwp + o1 + lb);
      ushort4 u2 = *(const ushort4*)(xwp + o2 + lb);
      ushort4 u3 = *(const ushort4*)(xwp + o3 + lb);
      accx += w0*b2f(u0.x) + w1*b2f(u1.x) + w2*b2f(u2.x) + w3*b2f(u3.x);
      accy += w0*b2f(u0.y) + w1*b2f(u1.y) + w2*b2f(u2.y) + w3*b2f(u3.y);
      accz += w0*b2f(u0.z) + w1*b2f(u1.z) + w2*b2f(u2.z) + w3*b2f(u3.z);
      accw += w0*b2f(u0.w) + w1*b2f(u1.w) + w2*b2f(u2.w) + w3*b2f(u3.w);
    }
    for (; q < deg; ++q){
      int o0 = sLds[w][q];
      float wh = eLds[w][h][q];
      ushort4 u = *(const ushort4*)(xwp + o0 + lb);
      accx += wh * b2f(u.x); accy += wh * b2f(u.y);
      accz += wh * b2f(u.z); accw += wh * b2f(u.w);
    }
  } else {
    float s0 = 0.f, s1 = 0.f, s2 = 0.f, s3 = 0.f;
    for (int j = lane; j < deg; j += 64){
      int s = csr_src[row0 + j];
      float4 a4 = *(const float4*)&as_[s * 4];
      s0 += __expf(lrelu(a4.x + ad4.x));
      s1 += __expf(lrelu(a4.y + ad4.y));
      s2 += __expf(lrelu(a4.z + ad4.z));
      s3 += __expf(lrelu(a4.w + ad4.w));
    }
    for (int m = 1; m < 64; m <<= 1){
      s0 += __shfl_xor(s0, m, 64); s1 += __shfl_xor(s1, m, 64);
      s2 += __shfl_xor(s2, m, 64); s3 += __shfl_xor(s3, m, 64);
    }
    sh = (h == 0) ? s0 : (h == 1) ? s1 : (h == 2) ? s2 : s3;
    for (int jb = 0; jb < deg; jb += 64){
      int jj = jb + lane;
      int soff = 0; float e0 = 0.f, e1 = 0.f, e2 = 0.f, e3 = 0.f;
      if (jj < deg){
        int sreg = csr_src[row0 + jj];
        soff = sreg * 512;
        float4 a4 = *(const float4*)&as_[sreg * 4];
        e0 = __expf(lrelu(a4.x + ad4.x));
        e1 = __expf(lrelu(a4.y + ad4.y));
        e2 = __expf(lrelu(a4.z + ad4.z));
        e3 = __expf(lrelu(a4.w + ad4.w));
      }
      sLds[w][lane] = soff;
      eLds[w][0][lane] = e0; eLds[w][1][lane] = e1;
      eLds[w][2][lane] = e2; eLds[w][3][lane] = e3;
      __builtin_amdgcn_s_waitcnt(0);
      int lim = min(64, deg - jb);
      for (int q = 0; q < lim; ++q){
        int o0 = sLds[w][q];
        float wh = eLds[w][h][q];
        ushort4 u = *(const ushort4*)(xwp + o0 + lb);
        accx += wh * b2f(u.x); accy += wh * b2f(u.y);
        accz += wh * b2f(u.z); accw += wh * b2f(u.w);
      }
    }
  }
  float invh = 1.f / (sh + 1e-16f);
  float4 b4 = *(const float4*)&bias[lane * 4];
  ushort4 o;
  o.x = f2b(accx * invh + b4.x); o.y = f2b(accy * invh + b4.y);
  o.z = f2b(accz * invh + b4.z); o.w = f2b(accw * invh + b4.w);
  *(ushort4*)&outb[(size_t)node * HF + lane * 4] = o;
}

// ---------------- GEMM2 fused: 3 instances, BN+ReLU staging, bf16 MFMA, normalize -> d_out ----------------
// Tile M=64, N=64 (full), K=3x256. 4 waves, wave w rows 16w..16w+15.
__global__ __launch_bounds__(256) void k_gemm2f(const unsigned short* __restrict__ ob0,
                                                const unsigned short* __restrict__ ob1,
                                                const unsigned short* __restrict__ ob2,
                                                const unsigned short* __restrict__ lwb,
                                                const float* __restrict__ scale,
                                                const float* __restrict__ shiftv,
                                                const float* __restrict__ linb,
                                                float* __restrict__ outp){
  __shared__ unsigned char Asm[64 * 512];   // 32KB (64 rows x 256 bf16)
  __shared__ unsigned char Bsm[64 * 512];   // 32KB
  int tid = threadIdx.x;
  int m0 = blockIdx.x * 64;
  int w = tid >> 6, lane = tid & 63;
  int l15 = lane & 15, l4 = lane >> 4;

  fl4 acc[4] = {};
  const unsigned short* obs[3] = {ob0, ob1, ob2};

  for (int i = 0; i < 3; ++i){
    if (i) __syncthreads();
    const unsigned short* A = obs[i];
    const float* sc = scale + i * HF;
    const float* sf = shiftv + i * HF;
    // stage A: 2048 16B chunks with BN+ReLU
    #pragma unroll
    for (int k = 0; k < 8; ++k){
      int c = k * 256 + tid;
      int row = c >> 5;
      int colb = (c & 31) * 16;
      int col = colb >> 1;
      int grow = m0 + row; if (grow >= N_NODES) grow = N_NODES - 1;
      us8 u = *(const us8*)&A[(size_t)grow * HF + col];
      float4 s0 = *(const float4*)&sc[col], s1 = *(const float4*)&sc[col + 4];
      float4 f0 = *(const float4*)&sf[col], f1 = *(const float4*)&sf[col + 4];
      us8 o;
      o[0] = f2b(fmaxf(0.f, b2f(u[0]) * s0.x + f0.x));
      o[1] = f2b(fmaxf(0.f, b2f(u[1]) * s0.y + f0.y));
      o[2] = f2b(fmaxf(0.f, b2f(u[2]) * s0.z + f0.z));
      o[3] = f2b(fmaxf(0.f, b2f(u[3]) * s0.w + f0.w));
      o[4] = f2b(fmaxf(0.f, b2f(u[4]) * s1.x + f1.x));
      o[5] = f2b(fmaxf(0.f, b2f(u[5]) * s1.y + f1.y));
      o[6] = f2b(fmaxf(0.f, b2f(u[6]) * s1.z + f1.z));
      o[7] = f2b(fmaxf(0.f, b2f(u[7]) * s1.w + f1.w));
      *(us8*)(Asm + row * 512 + (colb ^ ((row & 7) << 4))) = o;
    }
    // stage B
    const unsigned short* B = lwb + (size_t)i * HID * HF;
    #pragma unroll
    for (int k = 0; k < 8; ++k){
      int c = k * 256 + tid;
      int row = c >> 5;
      int colb = (c & 31) * 16;
      uint4 v = *(const uint4*)((const char*)B + (size_t)row * 512 + colb);
      *(uint4*)(Bsm + row * 512 + (colb ^ ((row & 7) << 4))) = v;
    }
    __syncthreads();
    #pragma unroll
    for (int kk = 0; kk < 8; ++kk){
      int ar = w * 16 + l15;
      int ac = (kk * 64 + l4 * 16) ^ ((ar & 7) << 4);
      bh8 af = *(const bh8*)(Asm + ar * 512 + ac);
      #pragma unroll
      for (int n = 0; n < 4; ++n){
        int br = n * 16 + l15;
        int bc = (kk * 64 + l4 * 16) ^ ((br & 7) << 4);
        bh8 bfv = *(const bh8*)(Bsm + br * 512 + bc);
        acc[n] = __builtin_amdgcn_mfma_f32_16x16x32_bf16(af, bfv, acc[n], 0, 0, 0);
      }
    }
  }
  float lbs[4];
  #pragma unroll
  for (int n = 0; n < 4; ++n){
    int c = n * 16 + l15;
    lbs[n] = linb[c] + linb[64 + c] + linb[128 + c];
  }
  #pragma unroll
  for (int j = 0; j < 4; ++j){
    float v0 = acc[0][j] + lbs[0];
    float v1 = acc[1][j] + lbs[1];
    float v2 = acc[2][j] + lbs[2];
    float v3 = acc[3][j] + lbs[3];
    float ss = v0*v0 + v1*v1 + v2*v2 + v3*v3;
    #pragma unroll
    for (int mm = 1; mm < 16; mm <<= 1) ss += __shfl_xor(ss, mm, 64);
    float rn = 1.f / sqrtf(ss);
    int grow = m0 + w * 16 + l4 * 4 + j;
    if (grow < N_NODES){
      float* op = outp + (size_t)grow * HID;
      op[l15]      = v0 * rn;
      op[16 + l15] = v1 * rn;
      op[32 + l15] = v2 * rn;
      op[48 + l15] = v3 * rn;
    }
  }
}

extern "C" void kernel_launch(void* const* d_in, const int* in_sizes, int n_in,
                              void* d_out, int out_size, void* d_ws, size_t ws_size,
                              hipStream_t stream){
  const float* sppmi   = (const float*)d_in[0];
  const float* W       = (const float*)d_in[1];
  const float* att_src = (const float*)d_in[2];
  const float* att_dst = (const float*)d_in[3];
  const float* bias    = (const float*)d_in[4];
  const float* bn_g    = (const float*)d_in[5];
  const float* bn_b    = (const float*)d_in[6];
  const float* bn_m    = (const float*)d_in[7];
  const float* bn_v    = (const float*)d_in[8];
  const float* lin_W   = (const float*)d_in[9];
  const float* lin_b   = (const float*)d_in[10];
  const int*   ei      = (const int*)d_in[11];

  char* ws = (char*)d_ws;
  size_t off = 0;
  auto alloc = [&](size_t bytes)->char*{ char* p = ws + off; off += (bytes + 255) & ~(size_t)255; return p; };
  unsigned short* wb   = (unsigned short*)alloc((size_t)3 * HF * IN_F * 2);
  unsigned short* lwb  = (unsigned short*)alloc((size_t)3 * HID * HF * 2);
  float* scale  = (float*)alloc((size_t)3 * HF * 4);
  float* shiftv = (float*)alloc((size_t)3 * HF * 4);
  unsigned short* xwb  = (unsigned short*)alloc((size_t)N_NODES * HF * 2);
  unsigned short* outb0 = (unsigned short*)alloc((size_t)N_NODES * HF * 2);
  unsigned short* outb1 = (unsigned short*)alloc((size_t)N_NODES * HF * 2);
  unsigned short* outb2 = (unsigned short*)alloc((size_t)N_NODES * HF * 2);
  float* as_    = (float*)alloc((size_t)N_NODES * 4 * 4);
  float* ad_    = (float*)alloc((size_t)N_NODES * 4 * 4);
  int* counts   = (int*)alloc((size_t)N_NODES * 4);
  int* row_ptr  = (int*)alloc((size_t)(N_NODES + 4) * 4);
  int* cursor   = (int*)alloc((size_t)N_NODES * 4);
  int* csr      = (int*)alloc((size_t)ET * 4);
  int* bsums    = (int*)alloc((size_t)NSCAN_BLK * 4);
  int* bexcl    = (int*)alloc((size_t)NSCAN_BLK * 4);
  unsigned short* obs[3] = {outb0, outb1, outb2};

  hipMemsetAsync(counts, 0, (size_t)N_NODES * 4, stream);

  k_cvt<<<96, 256, 0, stream>>>(W, wb, 3 * HF * IN_F / 4);
  k_cvt<<<48, 256, 0, stream>>>(lin_W, lwb, 3 * HID * HF / 4);
  k_bnprep<<<3, 256, 0, stream>>>(bn_g, bn_b, bn_m, bn_v, scale, shiftv);

  k_hist<<<(ET + 255) / 256, 256, 0, stream>>>(ei, counts);
  k_bsum<<<NSCAN_BLK, 256, 0, stream>>>(counts, bsums);
  k_bscan<<<1, 256, 0, stream>>>(bsums, bexcl, row_ptr);
  k_sfinal<<<NSCAN_BLK, 256, 0, stream>>>(counts, bexcl, row_ptr, cursor);
  k_scatter<<<(ET + 255) / 256, 256, 0, stream>>>(ei, cursor, csr);

  for (int i = 0; i < 3; ++i){
    k_gemm1f<<<1563, 256, 0, stream>>>(sppmi + (size_t)i * N_NODES * IN_F,
                                       wb + (size_t)i * HF * IN_F,
                                       att_src + i * HF, att_dst + i * HF,
                                       xwb, as_, ad_);
    k_agg<<<12500, 256, 0, stream>>>(xwb, as_, ad_, row_ptr, csr, bias + i * HF, obs[i]);
  }
  k_gemm2f<<<782, 256, 0, stream>>>(outb0, outb1, outb2, lwb, scale, shiftv,
                                    (const float*)d_in[10], (float*)d_out);
}

// Round 6
// 373.061 us; speedup vs baseline: 2.4606x; 1.0702x over previous
//
#include <hip/hip_runtime.h>
#include <hip/hip_bf16.h>

#define N_NODES 50000
#define E0      800000
#define ET      850000   // E0 + N_NODES self-loops
#define IN_F    128
#define HF      256
#define HID     64
#define NEG     0.2f
#define BN_EPSC 1e-5f
#define NSCAN_BLK 196    // ceil(50000/256)
#define HALF_F  128      // features per half (heads 0,1 | heads 2,3)

typedef __attribute__((ext_vector_type(8))) short bh8;            // 8 bf16 (4 VGPRs)
typedef __attribute__((ext_vector_type(4))) float fl4;            // 4 f32 accum
typedef __attribute__((ext_vector_type(8))) unsigned short us8;   // 8 u16

__device__ __forceinline__ float lrelu(float x){ return x > 0.f ? x : NEG * x; }
__device__ __forceinline__ unsigned short f2b(float f){
  unsigned int x = __float_as_uint(f);
  unsigned int r = x + 0x7FFF + ((x >> 16) & 1);   // RNE
  return (unsigned short)(r >> 16);
}
__device__ __forceinline__ float b2f(unsigned short u){
  return __uint_as_float((unsigned int)u << 16);
}

// ---------------- prep: W->bf16, linW->bf16, BN scale/shift (one launch) ----------------
#define NW4 (3 * HF * IN_F / 4)     // 24576
#define NL4 (3 * HID * HF / 4)      // 12288
__global__ __launch_bounds__(256) void k_prep(const float* __restrict__ W, unsigned short* __restrict__ wb,
                                              const float* __restrict__ linW, unsigned short* __restrict__ lwb,
                                              const float* __restrict__ g, const float* __restrict__ b,
                                              const float* __restrict__ m, const float* __restrict__ v,
                                              float* __restrict__ scale, float* __restrict__ shiftv){
  int idx = blockIdx.x * 256 + threadIdx.x;
  if (idx < NW4){
    float4 x = ((const float4*)W)[idx];
    ((ushort4*)wb)[idx] = make_ushort4(f2b(x.x), f2b(x.y), f2b(x.z), f2b(x.w));
  } else if (idx < NW4 + NL4){
    int j = idx - NW4;
    float4 x = ((const float4*)linW)[j];
    ((ushort4*)lwb)[j] = make_ushort4(f2b(x.x), f2b(x.y), f2b(x.z), f2b(x.w));
  } else if (idx < NW4 + NL4 + 3 * HF){
    int i = idx - NW4 - NL4;
    float s = g[i] * rsqrtf(v[i] + BN_EPSC);
    scale[i] = s;
    shiftv[i] = b[i] - m[i] * s;
  }
}

// ---------------- CSR build ----------------
__global__ void k_hist(const int* __restrict__ ei, int* __restrict__ counts){
  int e = blockIdx.x * 256 + threadIdx.x;
  if (e >= ET) return;
  int d = (e < E0) ? ei[E0 + e] : (e - E0);
  atomicAdd(&counts[d], 1);
}

__global__ __launch_bounds__(256) void k_bsum(const int* __restrict__ counts, int* __restrict__ bsums){
  int b = blockIdx.x;
  int t = threadIdx.x;
  int idx = b * 256 + t;
  int v = (idx < N_NODES) ? counts[idx] : 0;
  for (int m = 1; m < 64; m <<= 1) v += __shfl_xor(v, m, 64);
  __shared__ int ws[4];
  int lane = t & 63, w = t >> 6;
  if (lane == 0) ws[w] = v;
  __syncthreads();
  if (t == 0) bsums[b] = ws[0] + ws[1] + ws[2] + ws[3];
}

__global__ __launch_bounds__(256) void k_bscan(const int* __restrict__ bsums, int* __restrict__ bexcl,
                                               int* __restrict__ row_ptr){
  int t = threadIdx.x;
  int v = (t < NSCAN_BLK) ? bsums[t] : 0;
  int lane = t & 63, w = t >> 6;
  int incl = v;
  for (int m = 1; m < 64; m <<= 1){
    int n = __shfl_up(incl, m, 64);
    if (lane >= m) incl += n;
  }
  __shared__ int ws[4];
  if (lane == 63) ws[w] = incl;
  __syncthreads();
  if (t == 0){
    int r = 0;
    for (int j = 0; j < 4; ++j){ int x = ws[j]; ws[j] = r; r += x; }
  }
  __syncthreads();
  int excl = incl - v + ws[w];
  if (t < NSCAN_BLK) bexcl[t] = excl;
  if (t == 255) row_ptr[N_NODES] = excl + v;
}

__global__ __launch_bounds__(256) void k_sfinal(const int* __restrict__ counts,
                                                const int* __restrict__ bexcl,
                                                int* __restrict__ row_ptr, int* __restrict__ cursor){
  int b = blockIdx.x;
  int t = threadIdx.x;
  int idx = b * 256 + t;
  int v = (idx < N_NODES) ? counts[idx] : 0;
  int lane = t & 63, w = t >> 6;
  int incl = v;
  for (int m = 1; m < 64; m <<= 1){
    int n = __shfl_up(incl, m, 64);
    if (lane >= m) incl += n;
  }
  __shared__ int ws[4];
  if (lane == 63) ws[w] = incl;
  __syncthreads();
  if (t == 0){
    int r = 0;
    for (int j = 0; j < 4; ++j){ int x = ws[j]; ws[j] = r; r += x; }
  }
  __syncthreads();
  int excl = incl - v + ws[w];
  int pos = bexcl[b] + excl;
  if (idx < N_NODES){ row_ptr[idx] = pos; cursor[idx] = pos; }
}

__global__ void k_scatter(const int* __restrict__ ei, int* __restrict__ cursor,
                          int* __restrict__ csr_src){
  int e = blockIdx.x * 256 + threadIdx.x;
  if (e >= ET) return;
  int s, d;
  if (e < E0){ s = ei[e]; d = ei[E0 + e]; } else { s = e - E0; d = s; }
  int pos = atomicAdd(&cursor[d], 1);
  csr_src[pos] = s;
}

// ---------------- GEMM1 fused (all 3 instances): f32 A -> bf16 MFMA -> split xw + alpha ----------------
// Tile M=32, N=256. wave w == head w. xw3 layout: [inst][half][node][128] bf16.
__global__ __launch_bounds__(256) void k_gemm1f(const float* __restrict__ sppmi,
                                                const unsigned short* __restrict__ wb,
                                                const float* __restrict__ att_src,
                                                const float* __restrict__ att_dst,
                                                unsigned short* __restrict__ xw3,
                                                float* __restrict__ as3, float* __restrict__ ad3){
  __shared__ unsigned char Asm[32 * 256];    // 8KB
  __shared__ unsigned char Bsm[256 * 256];   // 64KB
  int tid = threadIdx.x;
  int bx = blockIdx.x;
  int inst = bx / 1563;
  int m0 = (bx % 1563) * 32;
  const float* x = sppmi + (size_t)inst * N_NODES * IN_F;
  const unsigned short* wbv = wb + (size_t)inst * HF * IN_F;
  const float* asrc = att_src + inst * HF;
  const float* adst = att_dst + inst * HF;
  float* as_ = as3 + (size_t)inst * N_NODES * 4;
  float* ad_ = ad3 + (size_t)inst * N_NODES * 4;

  // stage A with fused f32->bf16
  #pragma unroll
  for (int k = 0; k < 4; ++k){
    int c = k * 256 + tid;
    int row = c >> 5;
    int c4 = c & 31;
    int grow = m0 + row; if (grow >= N_NODES) grow = N_NODES - 1;
    float4 v = *(const float4*)&x[(size_t)grow * IN_F + c4 * 4];
    ushort4 o = make_ushort4(f2b(v.x), f2b(v.y), f2b(v.z), f2b(v.w));
    int colb = c4 * 8;
    int addr = row * 256 + ((colb & ~15) ^ ((row & 7) << 4)) + (colb & 15);
    *(ushort4*)(Asm + addr) = o;
  }
  // stage B
  #pragma unroll
  for (int k = 0; k < 16; ++k){
    int c = k * 256 + tid;
    int row = c >> 4;
    int colb = (c & 15) * 16;
    uint4 v = *(const uint4*)((const char*)wbv + (size_t)row * 256 + colb);
    *(uint4*)(Bsm + row * 256 + (colb ^ ((row & 7) << 4))) = v;
  }
  __syncthreads();

  int w = tid >> 6, lane = tid & 63;
  int l15 = lane & 15, l4 = lane >> 4;
  fl4 acc[2][4] = {};
  #pragma unroll
  for (int kk = 0; kk < 4; ++kk){
    bh8 af[2];
    #pragma unroll
    for (int m = 0; m < 2; ++m){
      int ar = m * 16 + l15;
      int ac = (kk * 64 + l4 * 16) ^ ((ar & 7) << 4);
      af[m] = *(const bh8*)(Asm + ar * 256 + ac);
    }
    bh8 bfv[4];
    #pragma unroll
    for (int n = 0; n < 4; ++n){
      int br = w * 64 + n * 16 + l15;
      int bc = (kk * 64 + l4 * 16) ^ ((br & 7) << 4);
      bfv[n] = *(const bh8*)(Bsm + br * 256 + bc);
    }
    #pragma unroll
    for (int m = 0; m < 2; ++m)
      #pragma unroll
      for (int n = 0; n < 4; ++n)
        acc[m][n] = __builtin_amdgcn_mfma_f32_16x16x32_bf16(af[m], bfv[n], acc[m][n], 0, 0, 0);
  }

  float asv[4], adv[4];
  #pragma unroll
  for (int n = 0; n < 4; ++n){
    int c = w * 64 + n * 16 + l15;
    asv[n] = asrc[c]; adv[n] = adst[c];
  }

  // write target: half = w>>1, col_in_half = (w&1)*64 + n*16 + l15
  unsigned short* xwh = xw3 + ((size_t)inst * 2 + (w >> 1)) * (size_t)N_NODES * HALF_F;
  int cbase = (w & 1) * 64;

  #pragma unroll
  for (int m = 0; m < 2; ++m){
    #pragma unroll
    for (int j = 0; j < 4; ++j){
      int grow = m0 + m * 16 + l4 * 4 + j;
      if (grow < N_NODES){
        #pragma unroll
        for (int n = 0; n < 4; ++n)
          xwh[(size_t)grow * HALF_F + cbase + n * 16 + l15] = f2b(acc[m][n][j]);
      }
      float ts = acc[m][0][j]*asv[0] + acc[m][1][j]*asv[1] + acc[m][2][j]*asv[2] + acc[m][3][j]*asv[3];
      float td = acc[m][0][j]*adv[0] + acc[m][1][j]*adv[1] + acc[m][2][j]*adv[2] + acc[m][3][j]*adv[3];
      #pragma unroll
      for (int mm = 1; mm < 16; mm <<= 1){ ts += __shfl_xor(ts, mm, 64); td += __shfl_xor(td, mm, 64); }
      if (l15 == 0 && grow < N_NODES){
        as_[grow * 4 + w] = ts;
        ad_[grow * 4 + w] = td;
      }
    }
  }
}

// ---------------- aggregation, all 3 instances, feature-half x XCD partitioned ----------------
// grid.x = 75000. inst = bx/25000; rem = bx%25000; half = (rem>>2)&1 (XCDs 0-3 vs 4-7);
// chunk = (rem>>3)*4 + (rem&3); 4 waves -> node = chunk*4 + w.
__global__ __launch_bounds__(256) void k_agg3(const unsigned short* __restrict__ xw3,
                     const float* __restrict__ as3, const float* __restrict__ ad3,
                     const int* __restrict__ row_ptr, const int* __restrict__ csr_src,
                     const float* __restrict__ bias, unsigned short* __restrict__ outb){
  __shared__ float eLds[4][2][65];
  __shared__ int   sLds[4][64];   // byte offsets within half-region (src * 256)
  int bx = blockIdx.x;
  int inst = bx / 25000;
  int rem = bx - inst * 25000;
  int half = (rem >> 2) & 1;
  int chunk = (rem >> 3) * 4 + (rem & 3);
  int w = threadIdx.x >> 6;
  int lane = threadIdx.x & 63;
  int node = chunk * 4 + w;
  int row0 = row_ptr[node];
  int deg = row_ptr[node + 1] - row0;
  const float* as_ = as3 + (size_t)inst * N_NODES * 4;
  const float* ad_ = ad3 + (size_t)inst * N_NODES * 4;
  float2 ad2 = *(const float2*)&ad_[node * 4 + half * 2];
  int head = lane >> 5;                 // cols lane*2,lane*2+1: head boundary at lane 32
  const char* xwp = (const char*)(xw3 + ((size_t)inst * 2 + half) * (size_t)N_NODES * HALF_F);
  int lb = lane * 4;
  float accx = 0.f, accy = 0.f;
  float sh;

  if (deg <= 64){
    int soff = 0; float e0 = 0.f, e1 = 0.f;
    if (lane < deg){
      int sreg = csr_src[row0 + lane];
      soff = sreg << 8;   // * 256B
      float2 a2 = *(const float2*)&as_[sreg * 4 + half * 2];
      e0 = __expf(lrelu(a2.x + ad2.x));
      e1 = __expf(lrelu(a2.y + ad2.y));
    }
    sLds[w][lane] = soff;
    eLds[w][0][lane] = e0; eLds[w][1][lane] = e1;
    float s0 = e0, s1 = e1;
    for (int m = 1; m < 64; m <<= 1){
      s0 += __shfl_xor(s0, m, 64); s1 += __shfl_xor(s1, m, 64);
    }
    sh = head ? s1 : s0;
    int q = 0;
    for (; q + 4 <= deg; q += 4){
      int o0 = sLds[w][q],   o1 = sLds[w][q+1];
      int o2 = sLds[w][q+2], o3 = sLds[w][q+3];
      float w0 = eLds[w][head][q],   w1 = eLds[w][head][q+1];
      float w2 = eLds[w][head][q+2], w3 = eLds[w][head][q+3];
      unsigned int u0 = *(const unsigned int*)(xwp + o0 + lb);
      unsigned int u1 = *(const unsigned int*)(xwp + o1 + lb);
      unsigned int u2 = *(const unsigned int*)(xwp + o2 + lb);
      unsigned int u3 = *(const unsigned int*)(xwp + o3 + lb);
      accx += w0*__uint_as_float(u0 << 16) + w1*__uint_as_float(u1 << 16)
            + w2*__uint_as_float(u2 << 16) + w3*__uint_as_float(u3 << 16);
      accy += w0*__uint_as_float(u0 & 0xffff0000u) + w1*__uint_as_float(u1 & 0xffff0000u)
            + w2*__uint_as_float(u2 & 0xffff0000u) + w3*__uint_as_float(u3 & 0xffff0000u);
    }
    for (; q < deg; ++q){
      int o0 = sLds[w][q];
      float wh = eLds[w][head][q];
      unsigned int u = *(const unsigned int*)(xwp + o0 + lb);
      accx += wh * __uint_as_float(u << 16);
      accy += wh * __uint_as_float(u & 0xffff0000u);
    }
  } else {
    float s0 = 0.f, s1 = 0.f;
    for (int j = lane; j < deg; j += 64){
      int s = csr_src[row0 + j];
      float2 a2 = *(const float2*)&as_[s * 4 + half * 2];
      s0 += __expf(lrelu(a2.x + ad2.x));
      s1 += __expf(lrelu(a2.y + ad2.y));
    }
    for (int m = 1; m < 64; m <<= 1){
      s0 += __shfl_xor(s0, m, 64); s1 += __shfl_xor(s1, m, 64);
    }
    sh = head ? s1 : s0;
    for (int jb = 0; jb < deg; jb += 64){
      int jj = jb + lane;
      int soff = 0; float e0 = 0.f, e1 = 0.f;
      if (jj < deg){
        int sreg = csr_src[row0 + jj];
        soff = sreg << 8;
        float2 a2 = *(const float2*)&as_[sreg * 4 + half * 2];
        e0 = __expf(lrelu(a2.x + ad2.x));
        e1 = __expf(lrelu(a2.y + ad2.y));
      }
      sLds[w][lane] = soff;
      eLds[w][0][lane] = e0; eLds[w][1][lane] = e1;
      __builtin_amdgcn_s_waitcnt(0);
      int lim = min(64, deg - jb);
      for (int q = 0; q < lim; ++q){
        int o0 = sLds[w][q];
        float wh = eLds[w][head][q];
        unsigned int u = *(const unsigned int*)(xwp + o0 + lb);
        accx += wh * __uint_as_float(u << 16);
        accy += wh * __uint_as_float(u & 0xffff0000u);
      }
    }
  }
  float invh = 1.f / (sh + 1e-16f);
  int col = half * HALF_F + lane * 2;
  float b0 = bias[inst * HF + col], b1 = bias[inst * HF + col + 1];
  ushort2 o;
  o.x = f2b(accx * invh + b0);
  o.y = f2b(accy * invh + b1);
  *(ushort2*)&outb[(size_t)inst * N_NODES * HF + (size_t)node * HF + col] = o;
}

// ---------------- GEMM2 fused: 3 instances, BN+ReLU staging, bf16 MFMA, normalize -> d_out ----------------
__global__ __launch_bounds__(256) void k_gemm2f(const unsigned short* __restrict__ obase,
                                                const unsigned short* __restrict__ lwb,
                                                const float* __restrict__ scale,
                                                const float* __restrict__ shiftv,
                                                const float* __restrict__ linb,
                                                float* __restrict__ outp){
  __shared__ unsigned char Asm[64 * 512];   // 32KB
  __shared__ unsigned char Bsm[64 * 512];   // 32KB
  int tid = threadIdx.x;
  int m0 = blockIdx.x * 64;
  int w = tid >> 6, lane = tid & 63;
  int l15 = lane & 15, l4 = lane >> 4;

  fl4 acc[4] = {};

  for (int i = 0; i < 3; ++i){
    if (i) __syncthreads();
    const unsigned short* A = obase + (size_t)i * N_NODES * HF;
    const float* sc = scale + i * HF;
    const float* sf = shiftv + i * HF;
    #pragma unroll
    for (int k = 0; k < 8; ++k){
      int c = k * 256 + tid;
      int row = c >> 5;
      int colb = (c & 31) * 16;
      int col = colb >> 1;
      int grow = m0 + row; if (grow >= N_NODES) grow = N_NODES - 1;
      us8 u = *(const us8*)&A[(size_t)grow * HF + col];
      float4 s0 = *(const float4*)&sc[col], s1 = *(const float4*)&sc[col + 4];
      float4 f0 = *(const float4*)&sf[col], f1 = *(const float4*)&sf[col + 4];
      us8 o;
      o[0] = f2b(fmaxf(0.f, b2f(u[0]) * s0.x + f0.x));
      o[1] = f2b(fmaxf(0.f, b2f(u[1]) * s0.y + f0.y));
      o[2] = f2b(fmaxf(0.f, b2f(u[2]) * s0.z + f0.z));
      o[3] = f2b(fmaxf(0.f, b2f(u[3]) * s0.w + f0.w));
      o[4] = f2b(fmaxf(0.f, b2f(u[4]) * s1.x + f1.x));
      o[5] = f2b(fmaxf(0.f, b2f(u[5]) * s1.y + f1.y));
      o[6] = f2b(fmaxf(0.f, b2f(u[6]) * s1.z + f1.z));
      o[7] = f2b(fmaxf(0.f, b2f(u[7]) * s1.w + f1.w));
      *(us8*)(Asm + row * 512 + (colb ^ ((row & 7) << 4))) = o;
    }
    const unsigned short* B = lwb + (size_t)i * HID * HF;
    #pragma unroll
    for (int k = 0; k < 8; ++k){
      int c = k * 256 + tid;
      int row = c >> 5;
      int colb = (c & 31) * 16;
      uint4 v = *(const uint4*)((const char*)B + (size_t)row * 512 + colb);
      *(uint4*)(Bsm + row * 512 + (colb ^ ((row & 7) << 4))) = v;
    }
    __syncthreads();
    #pragma unroll
    for (int kk = 0; kk < 8; ++kk){
      int ar = w * 16 + l15;
      int ac = (kk * 64 + l4 * 16) ^ ((ar & 7) << 4);
      bh8 af = *(const bh8*)(Asm + ar * 512 + ac);
      #pragma unroll
      for (int n = 0; n < 4; ++n){
        int br = n * 16 + l15;
        int bc = (kk * 64 + l4 * 16) ^ ((br & 7) << 4);
        bh8 bfv = *(const bh8*)(Bsm + br * 512 + bc);
        acc[n] = __builtin_amdgcn_mfma_f32_16x16x32_bf16(af, bfv, acc[n], 0, 0, 0);
      }
    }
  }
  float lbs[4];
  #pragma unroll
  for (int n = 0; n < 4; ++n){
    int c = n * 16 + l15;
    lbs[n] = linb[c] + linb[64 + c] + linb[128 + c];
  }
  #pragma unroll
  for (int j = 0; j < 4; ++j){
    float v0 = acc[0][j] + lbs[0];
    float v1 = acc[1][j] + lbs[1];
    float v2 = acc[2][j] + lbs[2];
    float v3 = acc[3][j] + lbs[3];
    float ss = v0*v0 + v1*v1 + v2*v2 + v3*v3;
    #pragma unroll
    for (int mm = 1; mm < 16; mm <<= 1) ss += __shfl_xor(ss, mm, 64);
    float rn = 1.f / sqrtf(ss);
    int grow = m0 + w * 16 + l4 * 4 + j;
    if (grow < N_NODES){
      float* op = outp + (size_t)grow * HID;
      op[l15]      = v0 * rn;
      op[16 + l15] = v1 * rn;
      op[32 + l15] = v2 * rn;
      op[48 + l15] = v3 * rn;
    }
  }
}

extern "C" void kernel_launch(void* const* d_in, const int* in_sizes, int n_in,
                              void* d_out, int out_size, void* d_ws, size_t ws_size,
                              hipStream_t stream){
  const float* sppmi   = (const float*)d_in[0];
  const float* W       = (const float*)d_in[1];
  const float* att_src = (const float*)d_in[2];
  const float* att_dst = (const float*)d_in[3];
  const float* bias    = (const float*)d_in[4];
  const float* bn_g    = (const float*)d_in[5];
  const float* bn_b    = (const float*)d_in[6];
  const float* bn_m    = (const float*)d_in[7];
  const float* bn_v    = (const float*)d_in[8];
  const float* lin_W   = (const float*)d_in[9];
  const float* lin_b   = (const float*)d_in[10];
  const int*   ei      = (const int*)d_in[11];

  char* ws = (char*)d_ws;
  size_t off = 0;
  auto alloc = [&](size_t bytes)->char*{ char* p = ws + off; off += (bytes + 255) & ~(size_t)255; return p; };
  unsigned short* wb   = (unsigned short*)alloc((size_t)3 * HF * IN_F * 2);
  unsigned short* lwb  = (unsigned short*)alloc((size_t)3 * HID * HF * 2);
  float* scale  = (float*)alloc((size_t)3 * HF * 4);
  float* shiftv = (float*)alloc((size_t)3 * HF * 4);
  unsigned short* xw3  = (unsigned short*)alloc((size_t)3 * 2 * N_NODES * HALF_F * 2);  // [inst][half][node][128]
  unsigned short* outb = (unsigned short*)alloc((size_t)3 * N_NODES * HF * 2);          // [inst][node][256]
  float* as3    = (float*)alloc((size_t)3 * N_NODES * 4 * 4);
  float* ad3    = (float*)alloc((size_t)3 * N_NODES * 4 * 4);
  int* counts   = (int*)alloc((size_t)N_NODES * 4);
  int* row_ptr  = (int*)alloc((size_t)(N_NODES + 4) * 4);
  int* cursor   = (int*)alloc((size_t)N_NODES * 4);
  int* csr      = (int*)alloc((size_t)ET * 4);
  int* bsums    = (int*)alloc((size_t)NSCAN_BLK * 4);
  int* bexcl    = (int*)alloc((size_t)NSCAN_BLK * 4);

  hipMemsetAsync(counts, 0, (size_t)N_NODES * 4, stream);

  k_prep<<<147, 256, 0, stream>>>(W, wb, lin_W, lwb, bn_g, bn_b, bn_m, bn_v, scale, shiftv);

  k_hist<<<(ET + 255) / 256, 256, 0, stream>>>(ei, counts);
  k_bsum<<<NSCAN_BLK, 256, 0, stream>>>(counts, bsums);
  k_bscan<<<1, 256, 0, stream>>>(bsums, bexcl, row_ptr);
  k_sfinal<<<NSCAN_BLK, 256, 0, stream>>>(counts, bexcl, row_ptr, cursor);
  k_scatter<<<(ET + 255) / 256, 256, 0, stream>>>(ei, cursor, csr);

  k_gemm1f<<<3 * 1563, 256, 0, stream>>>(sppmi, wb, att_src, att_dst, xw3, as3, ad3);
  k_agg3<<<75000, 256, 0, stream>>>(xw3, as3, ad3, row_ptr, csr, bias, outb);
  k_gemm2f<<<782, 256, 0, stream>>>(outb, lwb, scale, shiftv, lin_b, (float*)d_out);
}